// Round 13
// baseline (816.094 us; speedup 1.0000x reference)
//
#include <hip/hip_runtime.h>
#include <hip/hip_bf16.h>

typedef __bf16 bf16x8 __attribute__((ext_vector_type(8)));
typedef float  f32x4  __attribute__((ext_vector_type(4)));
typedef unsigned short u16x8 __attribute__((ext_vector_type(8)));

#define CH    256
#define IMG   112
#define WSZ   7
#define TOK   49
#define NWIN  4096
#define HID   512
#define NTHR  512

#define SX_ST 260          // f32 row stride for sX (permanent window buffer)

// ---- LDS arena (byte offsets), time-multiplexed ----
// [0, 51200)        sX f32 (whole kernel; becomes win2 in place at P6)
// [51200, 83968)    n1F frags -> (3b) V frags -> n2F frags
// [83968, 116736)   Q frags -> (4a) P bufs -> HM frags
// [116736, 149504)  K frags -> (4a) OF frags
#define OFF_AF   51200
#define OFF_V    51200
#define OFF_Q    83968
#define OFF_P    83968
#define PSZ      7168
#define OFF_HM   83968
#define OFF_K    116736
#define OFF_OF   116736
#define OFF_MR   149504     // sM[64], sR[64]
#define OFF_PRM  150016     // sG1,sB1,sG2,sB2 (each 256 f32)
#define SMEM_SZ  154112

// ---- d_ws layout: bf16 B-fragment blocks, 1KB each ----
#define WS_PROJ_BLK 384
#define WS_W1_BLK   512
#define WS_W2_BLK   768

__device__ __forceinline__ unsigned short f2bf(float f) {
    __bf16 h = (__bf16)f;
    return __builtin_bit_cast(unsigned short, h);
}

__device__ __forceinline__ f32x4 mfma16(bf16x8 a, bf16x8 b, f32x4 c) {
    return __builtin_amdgcn_mfma_f32_16x16x32_bf16(a, b, c, 0, 0, 0);
}

__device__ __forceinline__ int frOff(int base, int t, int c) {
    return base + (((t >> 4) * 8 + (c >> 5)) << 10)
                + (((((c >> 3) & 3) << 4) | (t & 15)) << 4)
                + ((c & 7) << 1);
}
__device__ __forceinline__ int frOffT(int base, int c, int t) {
    return base + ((((c >> 4) << 1) + (t >> 5)) << 10)
                + (((((t >> 3) & 3) << 4) | (c & 15)) << 4)
                + ((t & 7) << 1);
}

// ---------------- prepack: fp32 weights -> bf16 B-fragment blocks in d_ws ----------------
extern "C" __global__ __launch_bounds__(64)
void prepack(const float* __restrict__ qkv_w, const float* __restrict__ proj_w,
             const float* __restrict__ w1, const float* __restrict__ w2,
             char* __restrict__ ws)
{
    const int blk = blockIdx.x, l = threadIdx.x;
    const float* W; int nt, kt, ncols;
    if (blk < WS_PROJ_BLK)      { W = qkv_w;  int i = blk;               nt = i >> 3; kt = i & 7;  ncols = 768; }
    else if (blk < WS_W1_BLK)   { W = proj_w; int i = blk - WS_PROJ_BLK; nt = i >> 3; kt = i & 7;  ncols = 256; }
    else if (blk < WS_W2_BLK)   { W = w1;     int i = blk - WS_W1_BLK;   nt = i >> 3; kt = i & 7;  ncols = 512; }
    else                        { W = w2;     int i = blk - WS_W2_BLK;   nt = i >> 4; kt = i & 15; ncols = 256; }
    const int n  = nt * 16 + (l & 15);
    const int k0 = kt * 32 + (l >> 4) * 8;
    u16x8 o;
    #pragma unroll
    for (int j = 0; j < 8; ++j) o[j] = f2bf(W[(size_t)(k0 + j) * ncols + n]);
    *(u16x8*)(ws + (size_t)blk * 1024 + l * 16) = o;
}

// ---------------- main fused block: 8 waves, persistent sX, spill-free prefetch ----------------
extern "C" __global__ __launch_bounds__(NTHR, 1)
void swin_block(const float* __restrict__ x,
                const float* __restrict__ ln1_g, const float* __restrict__ ln1_b,
                const float* __restrict__ qkv_b,
                const float* __restrict__ proj_b,
                const float* __restrict__ ln2_g, const float* __restrict__ ln2_b,
                const float* __restrict__ b1, const float* __restrict__ b2,
                const char* __restrict__ ws,
                float* __restrict__ y)
{
    __shared__ __align__(16) char smem[SMEM_SZ];
    float* sX = (float*)(smem + 0);          // persistent; becomes win2 in place
    float* sM = (float*)(smem + OFF_MR);
    float* sR = sM + 64;
    float* sG1 = (float*)(smem + OFF_PRM);
    float* sB1 = sG1 + 256;
    float* sG2 = sB1 + 256;
    float* sB2 = sG2 + 256;

    const int tid  = threadIdx.x;
    const int wid  = tid >> 6;       // 0..7
    const int lane = tid & 63;
    const int sub  = lane >> 4;
    const int l15  = lane & 15;
    const int li7  = lane / 7;       // spatial row (lane<49)
    const int lj7  = lane - li7 * 7; // spatial col

    const int n  = blockIdx.x;
    const int b  = n >> 8;
    const int wh = (n >> 4) & 15;
    const int ww = n & 15;
    const int row0 = wh * WSZ, col0 = ww * WSZ;
    const size_t xbase = (size_t)b * CH * IMG * IMG;

    const f32x4 z4 = {0.f, 0.f, 0.f, 0.f};

    bf16x8 pbF0[8];      // proj tile-0 weights (filled late in P4, consumed in P6)

    // ---- P0: stage x -> sX (lane = spatial token, loop over channels) ----
    if (lane < TOK) {
        const float* xs = x + xbase + (size_t)(row0 + li7) * IMG + (col0 + lj7);
        float* dst = sX + lane * SX_ST;
        #pragma unroll 8
        for (int c = wid; c < CH; c += 8)
            dst[c] = xs[(size_t)c * (IMG * IMG)];
    }
    {
        int t2 = tid & 255;
        if (tid < 256) { sG1[t2] = ln1_g[t2]; sB1[t2] = ln1_b[t2]; }
        else           { sG2[t2] = ln2_g[t2]; sB2[t2] = ln2_b[t2]; }
    }
    __syncthreads();   // 1

    // ---- P1: LN1 stats ----
    for (int t = wid; t < TOK; t += 8) {
        const float4 v = *(const float4*)&sX[t * SX_ST + lane * 4];
        float s1 = v.x + v.y + v.z + v.w;
        float s2 = v.x * v.x + v.y * v.y + v.z * v.z + v.w * v.w;
        #pragma unroll
        for (int off = 32; off > 0; off >>= 1) {
            s1 += __shfl_xor(s1, off);
            s2 += __shfl_xor(s2, off);
        }
        if (lane == 0) {
            float m = s1 * (1.f / 256.f);
            float var = s2 * (1.f / 256.f) - m * m;
            sM[t] = m; sR[t] = rsqrtf(var + 1e-5f);
        }
    }
    __syncthreads();   // 2

    // prefetch first QKV B-batch (latency hides under P2; drains at barrier 3)
    bf16x8 bA[8], bB[8];
    #pragma unroll
    for (int kt = 0; kt < 8; ++kt)
        bA[kt] = *(const bf16x8*)(ws + (size_t)(((wid * 6) * 8 + kt) << 10) + lane * 16);

    // ---- P2: normalize -> n1F fragment blocks; zero pad rows ----
    for (int e = tid; e < 2048; e += NTHR) {
        int t = e & 63, cb = e >> 6;
        char* dst = smem + OFF_AF + (((t >> 4) * 8 + (cb >> 2)) << 10)
                  + (((((cb & 3) << 4) | (t & 15))) << 4);
        if (t < TOK) {
            const float* xr = sX + t * SX_ST + cb * 8;
            float4 xa = *(const float4*)xr;
            float4 xb = *(const float4*)(xr + 4);
            float m = sM[t], rs = sR[t];
            int c = cb * 8;
            u16x8 o;
            o[0] = f2bf((xa.x - m) * rs * sG1[c + 0] + sB1[c + 0]);
            o[1] = f2bf((xa.y - m) * rs * sG1[c + 1] + sB1[c + 1]);
            o[2] = f2bf((xa.z - m) * rs * sG1[c + 2] + sB1[c + 2]);
            o[3] = f2bf((xa.w - m) * rs * sG1[c + 3] + sB1[c + 3]);
            o[4] = f2bf((xb.x - m) * rs * sG1[c + 4] + sB1[c + 4]);
            o[5] = f2bf((xb.y - m) * rs * sG1[c + 5] + sB1[c + 5]);
            o[6] = f2bf((xb.z - m) * rs * sG1[c + 6] + sB1[c + 6]);
            o[7] = f2bf((xb.w - m) * rs * sG1[c + 7] + sB1[c + 7]);
            *(u16x8*)dst = o;
        } else {
            u16x8 z = {0, 0, 0, 0, 0, 0, 0, 0};
            *(u16x8*)dst = z;
        }
    }
    __syncthreads();   // 3

    // ---- P3: QKV GEMM (M=64,N=768,K=256); V frags overwrite n1F region after 3b ----
    {
        bf16x8 aF[4][8];
        #pragma unroll
        for (int mt = 0; mt < 4; ++mt)
            #pragma unroll
            for (int kt = 0; kt < 8; ++kt)
                aF[mt][kt] = *(const bf16x8*)(smem + OFF_AF + ((mt * 8 + kt) << 10) + lane * 16);
        __syncthreads();   // 3b: all waves hold n1F in regs; V may overwrite region

        auto qkv_epi = [&](int ntg, const f32x4 (&acc)[4]) {
            const float bias = qkv_b[ntg * 16 + l15];
            const int m3 = ntg >> 4;              // 0=Q 1=K 2=V
            const int c = (ntg & 15) * 16 + l15;
            if (m3 == 2) {
                #pragma unroll
                for (int mt = 0; mt < 4; ++mt)
                    #pragma unroll
                    for (int r = 0; r < 4; ++r) {
                        int t = mt * 16 + sub * 4 + r;
                        *(unsigned short*)(smem + frOffT(OFF_V, c, t)) = f2bf(acc[mt][r] + bias);
                    }
            } else if (m3 == 1) {
                #pragma unroll
                for (int mt = 0; mt < 4; ++mt)
                    #pragma unroll
                    for (int r = 0; r < 4; ++r) {
                        int t = mt * 16 + sub * 4 + r;
                        *(unsigned short*)(smem + frOff(OFF_K, t, c)) = f2bf(acc[mt][r] + bias);
                    }
            } else {
                #pragma unroll
                for (int mt = 0; mt < 4; ++mt)
                    #pragma unroll
                    for (int r = 0; r < 4; ++r) {
                        int t = mt * 16 + sub * 4 + r;
                        *(unsigned short*)(smem + frOff(OFF_Q, t, c)) = f2bf((acc[mt][r] + bias) * 0.125f);
                    }
            }
        };

        for (int i = 0; i < 6; i += 2) {
            const int n0 = wid * 6 + i;
            #pragma unroll
            for (int kt = 0; kt < 8; ++kt)
                bB[kt] = *(const bf16x8*)(ws + (size_t)(((n0 + 1) * 8 + kt) << 10) + lane * 16);
            {
                f32x4 acc[4] = {z4, z4, z4, z4};
                #pragma unroll
                for (int kt = 0; kt < 8; ++kt)
                    #pragma unroll
                    for (int mt = 0; mt < 4; ++mt)
                        acc[mt] = mfma16(aF[mt][kt], bA[kt], acc[mt]);
                qkv_epi(n0, acc);
            }
            if (i + 2 < 6) {
                #pragma unroll
                for (int kt = 0; kt < 8; ++kt)
                    bA[kt] = *(const bf16x8*)(ws + (size_t)(((n0 + 2) * 8 + kt) << 10) + lane * 16);
            }
            {
                f32x4 acc[4] = {z4, z4, z4, z4};
                #pragma unroll
                for (int kt = 0; kt < 8; ++kt)
                    #pragma unroll
                    for (int mt = 0; mt < 4; ++mt)
                        acc[mt] = mfma16(aF[mt][kt], bB[kt], acc[mt]);
                qkv_epi(n0 + 1, acc);
            }
        }
    }
    __syncthreads();   // 4

    // ---- P4: attention; wave = (head h = wid>>1, m-half ah = wid&1) ----
    {
        const int h  = wid >> 1;
        const int ah = wid & 1;
        f32x4 sc[2][4];
        #pragma unroll
        for (int m = 0; m < 2; ++m)
            #pragma unroll
            for (int nt = 0; nt < 4; ++nt) sc[m][nt] = z4;

        {
            bf16x8 qf[2][2], kf[4][2];
            #pragma unroll
            for (int m = 0; m < 2; ++m)
                #pragma unroll
                for (int k2 = 0; k2 < 2; ++k2)
                    qf[m][k2] = *(const bf16x8*)(smem + OFF_Q + (((ah * 2 + m) * 8 + h * 2 + k2) << 10) + lane * 16);
            #pragma unroll
            for (int nt = 0; nt < 4; ++nt)
                #pragma unroll
                for (int k2 = 0; k2 < 2; ++k2)
                    kf[nt][k2] = *(const bf16x8*)(smem + OFF_K + ((nt * 8 + h * 2 + k2) << 10) + lane * 16);
            #pragma unroll
            for (int k2 = 0; k2 < 2; ++k2)
                #pragma unroll
                for (int m = 0; m < 2; ++m)
                    #pragma unroll
                    for (int nt = 0; nt < 4; ++nt)
                        sc[m][nt] = mfma16(qf[m][k2], kf[nt][k2], sc[m][nt]);
        }
        __syncthreads();   // 4a: Q/K reads drained (P may overwrite Q region; OF may overwrite K region)

        const int pbase = OFF_P + h * PSZ;
        #pragma unroll
        for (int m = 0; m < 2; ++m) {
            #pragma unroll
            for (int r = 0; r < 4; ++r) {
                const int t = (ah * 2 + m) * 16 + sub * 4 + r;
                float v0 = sc[m][0][r];
                float v1 = sc[m][1][r];
                float v2 = sc[m][2][r];
                float v3 = (l15 == 0) ? sc[m][3][r] : -1e30f;
                float mx = fmaxf(fmaxf(v0, v1), fmaxf(v2, v3));
                mx = fmaxf(mx, __shfl_xor(mx, 1));
                mx = fmaxf(mx, __shfl_xor(mx, 2));
                mx = fmaxf(mx, __shfl_xor(mx, 4));
                mx = fmaxf(mx, __shfl_xor(mx, 8));
                float e0 = __expf(v0 - mx), e1 = __expf(v1 - mx);
                float e2 = __expf(v2 - mx), e3 = __expf(v3 - mx);
                float s = e0 + e1 + e2 + e3;
                s += __shfl_xor(s, 1);
                s += __shfl_xor(s, 2);
                s += __shfl_xor(s, 4);
                s += __shfl_xor(s, 8);
                float inv = 1.f / s;
                if (t < TOK) {
                    unsigned short* pr = (unsigned short*)(smem + pbase + t * 144);
                    pr[l15]      = f2bf(e0 * inv);
                    pr[16 + l15] = f2bf(e1 * inv);
                    pr[32 + l15] = f2bf(e2 * inv);
                    pr[48 + l15] = f2bf(e3 * inv);
                }
            }
        }

        // cross-barrier prefetch AFTER softmax (register peak over): proj tile-0 weights.
        // Latency hides under PV's fragment reads + MFMAs; drains at barrier 5.
        #pragma unroll
        for (int kt = 0; kt < 8; ++kt)
            pbF0[kt] = *(const bf16x8*)(ws + (size_t)(((WS_PROJ_BLK + (wid * 2) * 8 + kt)) << 10) + lane * 16);

        // PV: O_h rows of this m-half (P rows wave-local: same-wave write->read)
        bf16x8 pf[2][2], vf[4][2];
        #pragma unroll
        for (int m = 0; m < 2; ++m)
            #pragma unroll
            for (int k2 = 0; k2 < 2; ++k2) {
                int row = (ah * 2 + m) * 16 + l15; row = row > 48 ? 48 : row;
                pf[m][k2] = *(const bf16x8*)(smem + pbase + row * 144 + ((k2 * 32 + sub * 8) << 1));
            }
        #pragma unroll
        for (int nt = 0; nt < 4; ++nt)
            #pragma unroll
            for (int k2 = 0; k2 < 2; ++k2)
                vf[nt][k2] = *(const bf16x8*)(smem + OFF_V + ((((h * 4 + nt) << 1) + k2) << 10) + lane * 16);

        f32x4 oc[2][4];
        #pragma unroll
        for (int m = 0; m < 2; ++m)
            #pragma unroll
            for (int nt = 0; nt < 4; ++nt) oc[m][nt] = z4;
        #pragma unroll
        for (int k2 = 0; k2 < 2; ++k2)
            #pragma unroll
            for (int m = 0; m < 2; ++m)
                #pragma unroll
                for (int nt = 0; nt < 4; ++nt)
                    oc[m][nt] = mfma16(pf[m][k2], vf[nt][k2], oc[m][nt]);
        #pragma unroll
        for (int m = 0; m < 2; ++m)
            #pragma unroll
            for (int nt = 0; nt < 4; ++nt)
                #pragma unroll
                for (int r = 0; r < 4; ++r) {
                    int t = (ah * 2 + m) * 16 + sub * 4 + r;
                    int c = h * 64 + nt * 16 + l15;
                    *(unsigned short*)(smem + frOff(OFF_OF, t, c)) = f2bf(oc[m][nt][r]);
                }
    }
    __syncthreads();   // 5

    // ---- P6: proj + residual RMW into persistent sX ----
    float* sW = sX;
    {
        bf16x8 pbF1[8];
        #pragma unroll
        for (int kt = 0; kt < 8; ++kt)
            pbF1[kt] = *(const bf16x8*)(ws + (size_t)(((WS_PROJ_BLK + (wid * 2 + 1) * 8 + kt)) << 10) + lane * 16);

        bf16x8 aF[4][8];
        #pragma unroll
        for (int mt = 0; mt < 4; ++mt)
            #pragma unroll
            for (int kt = 0; kt < 8; ++kt)
                aF[mt][kt] = *(const bf16x8*)(smem + OFF_OF + ((mt * 8 + kt) << 10) + lane * 16);

        auto proj_epi = [&](int ntg, const f32x4 (&acc)[4]) {
            const int c = ntg * 16 + l15;
            const float bias = proj_b[c];
            #pragma unroll
            for (int mt = 0; mt < 4; ++mt)
                #pragma unroll
                for (int r = 0; r < 4; ++r) {
                    int t = mt * 16 + sub * 4 + r;
                    if (t < TOK) sW[t * SX_ST + c] += acc[mt][r] + bias;
                }
        };

        {
            f32x4 acc[4] = {z4, z4, z4, z4};
            #pragma unroll
            for (int kt = 0; kt < 8; ++kt)
                #pragma unroll
                for (int mt = 0; mt < 4; ++mt)
                    acc[mt] = mfma16(aF[mt][kt], pbF0[kt], acc[mt]);
            proj_epi(wid * 2, acc);
        }
        {
            f32x4 acc[4] = {z4, z4, z4, z4};
            #pragma unroll
            for (int kt = 0; kt < 8; ++kt)
                #pragma unroll
                for (int mt = 0; mt < 4; ++mt)
                    acc[mt] = mfma16(aF[mt][kt], pbF1[kt], acc[mt]);
            proj_epi(wid * 2 + 1, acc);
        }
    }
    __syncthreads();   // 6

    // ---- P7: LN2 stats ----
    for (int t = wid; t < TOK; t += 8) {
        const float4 v = *(const float4*)&sW[t * SX_ST + lane * 4];
        float s1 = v.x + v.y + v.z + v.w;
        float s2 = v.x * v.x + v.y * v.y + v.z * v.z + v.w * v.w;
        #pragma unroll
        for (int off = 32; off > 0; off >>= 1) {
            s1 += __shfl_xor(s1, off);
            s2 += __shfl_xor(s2, off);
        }
        if (lane == 0) {
            float m = s1 * (1.f / 256.f);
            float var = s2 * (1.f / 256.f) - m * m;
            sM[t] = m; sR[t] = rsqrtf(var + 1e-5f);
        }
    }
    __syncthreads();   // 7

    // prefetch MLP1 half-0 tile-0 weights (register-light phase; drains at barrier 8)
    bf16x8 pbW1[8];
    #pragma unroll
    for (int kt = 0; kt < 8; ++kt)
        pbW1[kt] = *(const bf16x8*)(ws + (size_t)(((WS_W1_BLK + (wid * 2) * 8 + kt)) << 10) + lane * 16);

    // ---- P8: LN2 normalize -> n2F ----
    for (int e = tid; e < 2048; e += NTHR) {
        int t = e & 63, cb = e >> 6;
        char* dst = smem + OFF_AF + (((t >> 4) * 8 + (cb >> 2)) << 10)
                  + (((((cb & 3) << 4) | (t & 15))) << 4);
        if (t < TOK) {
            const float* xr = sW + t * SX_ST + cb * 8;
            float4 xa = *(const float4*)xr;
            float4 xb = *(const float4*)(xr + 4);
            float m = sM[t], rs = sR[t];
            int c = cb * 8;
            u16x8 o;
            o[0] = f2bf((xa.x - m) * rs * sG2[c + 0] + sB2[c + 0]);
            o[1] = f2bf((xa.y - m) * rs * sG2[c + 1] + sB2[c + 1]);
            o[2] = f2bf((xa.z - m) * rs * sG2[c + 2] + sB2[c + 2]);
            o[3] = f2bf((xa.w - m) * rs * sG2[c + 3] + sB2[c + 3]);
            o[4] = f2bf((xb.x - m) * rs * sG2[c + 4] + sB2[c + 4]);
            o[5] = f2bf((xb.y - m) * rs * sG2[c + 5] + sB2[c + 5]);
            o[6] = f2bf((xb.z - m) * rs * sG2[c + 6] + sB2[c + 6]);
            o[7] = f2bf((xb.w - m) * rs * sG2[c + 7] + sB2[c + 7]);
            *(u16x8*)dst = o;
        } else {
            u16x8 z = {0, 0, 0, 0, 0, 0, 0, 0};
            *(u16x8*)dst = z;
        }
    }
    __syncthreads();   // 8

    // ---- P9: MLP in two K-halves; single weight-tile register set per phase ----
    {
        f32x4 acc2[2][4];
        #pragma unroll
        for (int i = 0; i < 2; ++i)
            #pragma unroll
            for (int mt = 0; mt < 4; ++mt) acc2[i][mt] = z4;

        for (int half = 0; half < 2; ++half) {
            // MLP1: tile0 weights (prefetched for half 0), MFMA0, reload tile1 under epi0
            {
                bf16x8 bF[8];
                if (half == 0) {
                    #pragma unroll
                    for (int kt = 0; kt < 8; ++kt) bF[kt] = pbW1[kt];
                } else {
                    #pragma unroll
                    for (int kt = 0; kt < 8; ++kt)
                        bF[kt] = *(const bf16x8*)(ws + (size_t)(((WS_W1_BLK + (half * 16 + wid * 2) * 8 + kt)) << 10) + lane * 16);
                }
                bf16x8 nf[4][8];
                #pragma unroll
                for (int mt = 0; mt < 4; ++mt)
                    #pragma unroll
                    for (int kt = 0; kt < 8; ++kt)
                        nf[mt][kt] = *(const bf16x8*)(smem + OFF_AF + ((mt * 8 + kt) << 10) + lane * 16);

                auto mlp1_epi = [&](int ntg, const f32x4 (&acc)[4]) {
                    const int chm = ntg * 16 + l15;
                    const float bias = b1[half * 256 + chm];
                    #pragma unroll
                    for (int mt = 0; mt < 4; ++mt)
                        #pragma unroll
                        for (int r = 0; r < 4; ++r) {
                            int t = mt * 16 + sub * 4 + r;
                            if (t < TOK) {
                                float v = acc[mt][r] + bias;
                                float u = v * (1.5957691216f + 0.07135481627f * v * v);
                                float g = v / (1.f + __expf(-u));
                                *(unsigned short*)(smem + frOff(OFF_HM, t, chm)) = f2bf(g);
                            }
                        }
                };

                f32x4 acc[4] = {z4, z4, z4, z4};
                #pragma unroll
                for (int kt = 0; kt < 8; ++kt)
                    #pragma unroll
                    for (int mt = 0; mt < 4; ++mt)
                        acc[mt] = mfma16(nf[mt][kt], bF[kt], acc[mt]);
                // reload bF with tile1 now; latency hides under tile0 epilogue
                #pragma unroll
                for (int kt = 0; kt < 8; ++kt)
                    bF[kt] = *(const bf16x8*)(ws + (size_t)(((WS_W1_BLK + (half * 16 + wid * 2 + 1) * 8 + kt)) << 10) + lane * 16);
                mlp1_epi(wid * 2, acc);

                f32x4 acc1[4] = {z4, z4, z4, z4};
                #pragma unroll
                for (int kt = 0; kt < 8; ++kt)
                    #pragma unroll
                    for (int mt = 0; mt < 4; ++mt)
                        acc1[mt] = mfma16(nf[mt][kt], bF[kt], acc1[mt]);
                mlp1_epi(wid * 2 + 1, acc1);
            }
            __syncthreads();   // HM ready

            // MLP2 partial: single bF set, reloaded between tiles
            {
                bf16x8 bF[8];
                #pragma unroll
                for (int kt = 0; kt < 8; ++kt)
                    bF[kt] = *(const bf16x8*)(ws + (size_t)(((WS_W2_BLK + (wid * 2 + 0) * 16 + half * 8 + kt)) << 10) + lane * 16);
                bf16x8 hf[4][8];
                #pragma unroll
                for (int mt = 0; mt < 4; ++mt)
                    #pragma unroll
                    for (int kt = 0; kt < 8; ++kt)
                        hf[mt][kt] = *(const bf16x8*)(smem + OFF_HM + ((mt * 8 + kt) << 10) + lane * 16);

                #pragma unroll
                for (int kt = 0; kt < 8; ++kt)
                    #pragma unroll
                    for (int mt = 0; mt < 4; ++mt)
                        acc2[0][mt] = mfma16(hf[mt][kt], bF[kt], acc2[0][mt]);
                #pragma unroll
                for (int kt = 0; kt < 8; ++kt)
                    bF[kt] = *(const bf16x8*)(ws + (size_t)(((WS_W2_BLK + (wid * 2 + 1) * 16 + half * 8 + kt)) << 10) + lane * 16);
                #pragma unroll
                for (int kt = 0; kt < 8; ++kt)
                    #pragma unroll
                    for (int mt = 0; mt < 4; ++mt)
                        acc2[1][mt] = mfma16(hf[mt][kt], bF[kt], acc2[1][mt]);
            }
            __syncthreads();   // HM reads done
        }

        // epilogue: win2 += mlp2 + b2
        #pragma unroll
        for (int i = 0; i < 2; ++i) {
            const int c = (wid * 2 + i) * 16 + l15;
            const float bias = b2[c];
            #pragma unroll
            for (int mt = 0; mt < 4; ++mt)
                #pragma unroll
                for (int r = 0; r < 4; ++r) {
                    int t = mt * 16 + sub * 4 + r;
                    if (t < TOK) sW[t * SX_ST + c] += acc2[i][mt][r] + bias;
                }
        }
    }
    __syncthreads();   // final

    // ---- P10: window-reverse store (lane = spatial token) ----
    if (lane < TOK) {
        float* ys = y + xbase + (size_t)(row0 + li7) * IMG + (col0 + lj7);
        const float* src = sW + lane * SX_ST;
        #pragma unroll 8
        for (int c = wid; c < CH; c += 8)
            ys[(size_t)c * (IMG * IMG)] = src[c];
    }
}

extern "C" void kernel_launch(void* const* d_in, const int* in_sizes, int n_in,
                              void* d_out, int out_size, void* d_ws, size_t ws_size,
                              hipStream_t stream) {
    const float* x      = (const float*)d_in[0];
    const float* ln1_g  = (const float*)d_in[1];
    const float* ln1_b  = (const float*)d_in[2];
    const float* qkv_w  = (const float*)d_in[3];
    const float* qkv_b  = (const float*)d_in[4];
    const float* proj_w = (const float*)d_in[5];
    const float* proj_b = (const float*)d_in[6];
    const float* ln2_g  = (const float*)d_in[7];
    const float* ln2_b  = (const float*)d_in[8];
    const float* w1     = (const float*)d_in[9];
    const float* b1     = (const float*)d_in[10];
    const float* w2     = (const float*)d_in[11];
    const float* b2     = (const float*)d_in[12];

    hipLaunchKernelGGL(prepack, dim3(1024), dim3(64), 0, stream,
                       qkv_w, proj_w, w1, w2, (char*)d_ws);
    hipLaunchKernelGGL(swin_block, dim3(NWIN), dim3(NTHR), 0, stream,
                       x, ln1_g, ln1_b, qkv_b, proj_b, ln2_g, ln2_b, b1, b2,
                       (const char*)d_ws, (float*)d_out);
}

// Round 14
// 732.839 us; speedup vs baseline: 1.1136x; 1.1136x over previous
//
#include <hip/hip_runtime.h>
#include <hip/hip_bf16.h>

typedef __bf16 bf16x8 __attribute__((ext_vector_type(8)));
typedef float  f32x4  __attribute__((ext_vector_type(4)));
typedef unsigned short u16x8 __attribute__((ext_vector_type(8)));

#define CH    256
#define IMG   112
#define WSZ   7
#define TOK   49
#define NWIN  4096
#define HID   512
#define NTHR  512

#define SX_ST 260          // f32 row stride for sX (permanent window buffer)

// ---- LDS arena (byte offsets), time-multiplexed ----
// [0, 51200)        sX f32 (whole kernel; becomes win2 in place at P6)
// [51200, 83968)    n1F frags -> (3b) V frags -> n2F frags
// [83968, 116736)   Q frags -> (4a) P bufs -> HM frags
// [116736, 149504)  K frags -> (4a) OF frags
#define OFF_AF   51200
#define OFF_V    51200
#define OFF_Q    83968
#define OFF_P    83968
#define PSZ      7168
#define OFF_HM   83968
#define OFF_K    116736
#define OFF_OF   116736
#define OFF_MR   149504     // sM[64], sR[64]
#define OFF_PRM  150016     // sG1,sB1,sG2,sB2 (each 256 f32)
#define OFF_PART 154112     // float2[49*8] LN1 partials
#define SMEM_SZ  157248

// ---- d_ws layout: bf16 B-fragment blocks, 1KB each ----
#define WS_PROJ_BLK 384
#define WS_W1_BLK   512
#define WS_W2_BLK   768

__device__ __forceinline__ unsigned short f2bf(float f) {
    __bf16 h = (__bf16)f;
    return __builtin_bit_cast(unsigned short, h);
}

__device__ __forceinline__ f32x4 mfma16(bf16x8 a, bf16x8 b, f32x4 c) {
    return __builtin_amdgcn_mfma_f32_16x16x32_bf16(a, b, c, 0, 0, 0);
}

__device__ __forceinline__ int frOff(int base, int t, int c) {
    return base + (((t >> 4) * 8 + (c >> 5)) << 10)
                + (((((c >> 3) & 3) << 4) | (t & 15)) << 4)
                + ((c & 7) << 1);
}
__device__ __forceinline__ int frOffT(int base, int c, int t) {
    return base + ((((c >> 4) << 1) + (t >> 5)) << 10)
                + (((((t >> 3) & 3) << 4) | (c & 15)) << 4)
                + ((t & 7) << 1);
}

// ---------------- prepack: fp32 weights -> bf16 B-fragment blocks in d_ws ----------------
extern "C" __global__ __launch_bounds__(64)
void prepack(const float* __restrict__ qkv_w, const float* __restrict__ proj_w,
             const float* __restrict__ w1, const float* __restrict__ w2,
             char* __restrict__ ws)
{
    const int blk = blockIdx.x, l = threadIdx.x;
    const float* W; int nt, kt, ncols;
    if (blk < WS_PROJ_BLK)      { W = qkv_w;  int i = blk;               nt = i >> 3; kt = i & 7;  ncols = 768; }
    else if (blk < WS_W1_BLK)   { W = proj_w; int i = blk - WS_PROJ_BLK; nt = i >> 3; kt = i & 7;  ncols = 256; }
    else if (blk < WS_W2_BLK)   { W = w1;     int i = blk - WS_W1_BLK;   nt = i >> 3; kt = i & 7;  ncols = 512; }
    else                        { W = w2;     int i = blk - WS_W2_BLK;   nt = i >> 4; kt = i & 15; ncols = 256; }
    const int n  = nt * 16 + (l & 15);
    const int k0 = kt * 32 + (l >> 4) * 8;
    u16x8 o;
    #pragma unroll
    for (int j = 0; j < 8; ++j) o[j] = f2bf(W[(size_t)(k0 + j) * ncols + n]);
    *(u16x8*)(ws + (size_t)blk * 1024 + l * 16) = o;
}

// ---------------- main fused block: 8 waves, persistent sX, fused LN1, mt-split MLP ----------------
extern "C" __global__ __launch_bounds__(NTHR, 1)
void swin_block(const float* __restrict__ x,
                const float* __restrict__ ln1_g, const float* __restrict__ ln1_b,
                const float* __restrict__ qkv_b,
                const float* __restrict__ proj_b,
                const float* __restrict__ ln2_g, const float* __restrict__ ln2_b,
                const float* __restrict__ b1, const float* __restrict__ b2,
                const char* __restrict__ ws,
                float* __restrict__ y)
{
    __shared__ __align__(16) char smem[SMEM_SZ];
    float*  sX = (float*)(smem + 0);          // persistent; becomes win2 in place
    float*  sM = (float*)(smem + OFF_MR);
    float*  sR = sM + 64;
    float*  sG1 = (float*)(smem + OFF_PRM);
    float*  sB1 = sG1 + 256;
    float*  sG2 = sB1 + 256;
    float*  sB2 = sG2 + 256;
    float2* sPart = (float2*)(smem + OFF_PART);

    const int tid  = threadIdx.x;
    const int wid  = tid >> 6;       // 0..7
    const int lane = tid & 63;
    const int sub  = lane >> 4;
    const int l15  = lane & 15;
    const int li7  = lane / 7;       // spatial row (lane<49)
    const int lj7  = lane - li7 * 7; // spatial col

    const int n  = blockIdx.x;
    const int b  = n >> 8;
    const int wh = (n >> 4) & 15;
    const int ww = n & 15;
    const int row0 = wh * WSZ, col0 = ww * WSZ;
    const size_t xbase = (size_t)b * CH * IMG * IMG;

    const f32x4 z4 = {0.f, 0.f, 0.f, 0.f};

    bf16x8 pbF0[8];      // proj tile-0 weights (filled in P4, consumed in P6)

    // ---- P0: stage x -> sX with fused LN1 partial sums ----
    {
        float ps1 = 0.f, ps2 = 0.f;
        if (lane < TOK) {
            const float* xs = x + xbase + (size_t)(row0 + li7) * IMG + (col0 + lj7);
            float* dst = sX + lane * SX_ST;
            #pragma unroll 8
            for (int c = wid; c < CH; c += 8) {
                float v = xs[(size_t)c * (IMG * IMG)];
                dst[c] = v;
                ps1 += v; ps2 += v * v;
            }
        }
        int t2 = tid & 255;
        if (tid < 256) { sG1[t2] = ln1_g[t2]; sB1[t2] = ln1_b[t2]; }
        else           { sG2[t2] = ln2_g[t2]; sB2[t2] = ln2_b[t2]; }
        if (lane < TOK) sPart[lane * 8 + wid] = make_float2(ps1, ps2);
    }
    __syncthreads();   // 1

    // ---- P1: LN1 finalize (tiny) ----
    if (tid < TOK) {
        float s1 = 0.f, s2 = 0.f;
        #pragma unroll
        for (int w = 0; w < 8; ++w) {
            float2 q = sPart[tid * 8 + w];
            s1 += q.x; s2 += q.y;
        }
        float m = s1 * (1.f / 256.f);
        float var = s2 * (1.f / 256.f) - m * m;
        sM[tid] = m; sR[tid] = rsqrtf(var + 1e-5f);
    }
    __syncthreads();   // 2

    // prefetch first QKV B-batch (latency hides under P2; drains at barrier 3)
    bf16x8 bA[8], bB[8];
    #pragma unroll
    for (int kt = 0; kt < 8; ++kt)
        bA[kt] = *(const bf16x8*)(ws + (size_t)(((wid * 6) * 8 + kt) << 10) + lane * 16);

    // ---- P2: normalize -> n1F fragment blocks; zero pad rows ----
    for (int e = tid; e < 2048; e += NTHR) {
        int t = e & 63, cb = e >> 6;
        char* dst = smem + OFF_AF + (((t >> 4) * 8 + (cb >> 2)) << 10)
                  + (((((cb & 3) << 4) | (t & 15))) << 4);
        if (t < TOK) {
            const float* xr = sX + t * SX_ST + cb * 8;
            float4 xa = *(const float4*)xr;
            float4 xb = *(const float4*)(xr + 4);
            float m = sM[t], rs = sR[t];
            int c = cb * 8;
            u16x8 o;
            o[0] = f2bf((xa.x - m) * rs * sG1[c + 0] + sB1[c + 0]);
            o[1] = f2bf((xa.y - m) * rs * sG1[c + 1] + sB1[c + 1]);
            o[2] = f2bf((xa.z - m) * rs * sG1[c + 2] + sB1[c + 2]);
            o[3] = f2bf((xa.w - m) * rs * sG1[c + 3] + sB1[c + 3]);
            o[4] = f2bf((xb.x - m) * rs * sG1[c + 4] + sB1[c + 4]);
            o[5] = f2bf((xb.y - m) * rs * sG1[c + 5] + sB1[c + 5]);
            o[6] = f2bf((xb.z - m) * rs * sG1[c + 6] + sB1[c + 6]);
            o[7] = f2bf((xb.w - m) * rs * sG1[c + 7] + sB1[c + 7]);
            *(u16x8*)dst = o;
        } else {
            u16x8 z = {0, 0, 0, 0, 0, 0, 0, 0};
            *(u16x8*)dst = z;
        }
    }
    __syncthreads();   // 3

    // ---- P3: QKV GEMM (M=64,N=768,K=256); V frags overwrite n1F region after 3b ----
    {
        bf16x8 aF[4][8];
        #pragma unroll
        for (int mt = 0; mt < 4; ++mt)
            #pragma unroll
            for (int kt = 0; kt < 8; ++kt)
                aF[mt][kt] = *(const bf16x8*)(smem + OFF_AF + ((mt * 8 + kt) << 10) + lane * 16);
        __syncthreads();   // 3b: all waves hold n1F in regs; V may overwrite region

        auto qkv_epi = [&](int ntg, const f32x4 (&acc)[4]) {
            const float bias = qkv_b[ntg * 16 + l15];
            const int m3 = ntg >> 4;              // 0=Q 1=K 2=V
            const int c = (ntg & 15) * 16 + l15;
            if (m3 == 2) {
                #pragma unroll
                for (int mt = 0; mt < 4; ++mt)
                    #pragma unroll
                    for (int r = 0; r < 4; ++r) {
                        int t = mt * 16 + sub * 4 + r;
                        *(unsigned short*)(smem + frOffT(OFF_V, c, t)) = f2bf(acc[mt][r] + bias);
                    }
            } else if (m3 == 1) {
                #pragma unroll
                for (int mt = 0; mt < 4; ++mt)
                    #pragma unroll
                    for (int r = 0; r < 4; ++r) {
                        int t = mt * 16 + sub * 4 + r;
                        *(unsigned short*)(smem + frOff(OFF_K, t, c)) = f2bf(acc[mt][r] + bias);
                    }
            } else {
                #pragma unroll
                for (int mt = 0; mt < 4; ++mt)
                    #pragma unroll
                    for (int r = 0; r < 4; ++r) {
                        int t = mt * 16 + sub * 4 + r;
                        *(unsigned short*)(smem + frOff(OFF_Q, t, c)) = f2bf((acc[mt][r] + bias) * 0.125f);
                    }
            }
        };

        for (int i = 0; i < 6; i += 2) {
            const int n0 = wid * 6 + i;
            #pragma unroll
            for (int kt = 0; kt < 8; ++kt)
                bB[kt] = *(const bf16x8*)(ws + (size_t)(((n0 + 1) * 8 + kt) << 10) + lane * 16);
            {
                f32x4 acc[4] = {z4, z4, z4, z4};
                #pragma unroll
                for (int kt = 0; kt < 8; ++kt)
                    #pragma unroll
                    for (int mt = 0; mt < 4; ++mt)
                        acc[mt] = mfma16(aF[mt][kt], bA[kt], acc[mt]);
                qkv_epi(n0, acc);
            }
            if (i + 2 < 6) {
                #pragma unroll
                for (int kt = 0; kt < 8; ++kt)
                    bA[kt] = *(const bf16x8*)(ws + (size_t)(((n0 + 2) * 8 + kt) << 10) + lane * 16);
            }
            {
                f32x4 acc[4] = {z4, z4, z4, z4};
                #pragma unroll
                for (int kt = 0; kt < 8; ++kt)
                    #pragma unroll
                    for (int mt = 0; mt < 4; ++mt)
                        acc[mt] = mfma16(aF[mt][kt], bB[kt], acc[mt]);
                qkv_epi(n0 + 1, acc);
            }
        }
    }
    __syncthreads();   // 4

    // ---- P4: attention; wave = (head h = wid>>1, m-half ah = wid&1) ----
    {
        const int h  = wid >> 1;
        const int ah = wid & 1;
        f32x4 sc[2][4];
        #pragma unroll
        for (int m = 0; m < 2; ++m)
            #pragma unroll
            for (int nt = 0; nt < 4; ++nt) sc[m][nt] = z4;

        {
            bf16x8 qf[2][2], kf[4][2];
            #pragma unroll
            for (int m = 0; m < 2; ++m)
                #pragma unroll
                for (int k2 = 0; k2 < 2; ++k2)
                    qf[m][k2] = *(const bf16x8*)(smem + OFF_Q + (((ah * 2 + m) * 8 + h * 2 + k2) << 10) + lane * 16);
            #pragma unroll
            for (int nt = 0; nt < 4; ++nt)
                #pragma unroll
                for (int k2 = 0; k2 < 2; ++k2)
                    kf[nt][k2] = *(const bf16x8*)(smem + OFF_K + ((nt * 8 + h * 2 + k2) << 10) + lane * 16);
            #pragma unroll
            for (int k2 = 0; k2 < 2; ++k2)
                #pragma unroll
                for (int m = 0; m < 2; ++m)
                    #pragma unroll
                    for (int nt = 0; nt < 4; ++nt)
                        sc[m][nt] = mfma16(qf[m][k2], kf[nt][k2], sc[m][nt]);
        }
        __syncthreads();   // 4a: Q/K reads drained (P may overwrite Q region; OF may overwrite K region)

        // cross-barrier prefetch: proj tile-0 weights (consumed in P6; hides under softmax/PV)
        #pragma unroll
        for (int kt = 0; kt < 8; ++kt)
            pbF0[kt] = *(const bf16x8*)(ws + (size_t)(((WS_PROJ_BLK + (wid * 2) * 8 + kt)) << 10) + lane * 16);

        const int pbase = OFF_P + h * PSZ;
        #pragma unroll
        for (int m = 0; m < 2; ++m) {
            #pragma unroll
            for (int r = 0; r < 4; ++r) {
                const int t = (ah * 2 + m) * 16 + sub * 4 + r;
                float v0 = sc[m][0][r];
                float v1 = sc[m][1][r];
                float v2 = sc[m][2][r];
                float v3 = (l15 == 0) ? sc[m][3][r] : -1e30f;
                float mx = fmaxf(fmaxf(v0, v1), fmaxf(v2, v3));
                mx = fmaxf(mx, __shfl_xor(mx, 1));
                mx = fmaxf(mx, __shfl_xor(mx, 2));
                mx = fmaxf(mx, __shfl_xor(mx, 4));
                mx = fmaxf(mx, __shfl_xor(mx, 8));
                float e0 = __expf(v0 - mx), e1 = __expf(v1 - mx);
                float e2 = __expf(v2 - mx), e3 = __expf(v3 - mx);
                float s = e0 + e1 + e2 + e3;
                s += __shfl_xor(s, 1);
                s += __shfl_xor(s, 2);
                s += __shfl_xor(s, 4);
                s += __shfl_xor(s, 8);
                float inv = 1.f / s;
                if (t < TOK) {
                    unsigned short* pr = (unsigned short*)(smem + pbase + t * 144);
                    pr[l15]      = f2bf(e0 * inv);
                    pr[16 + l15] = f2bf(e1 * inv);
                    pr[32 + l15] = f2bf(e2 * inv);
                    pr[48 + l15] = f2bf(e3 * inv);
                }
            }
        }

        // PV: O_h rows of this m-half (P rows wave-local: same-wave write->read)
        bf16x8 pf[2][2], vf[4][2];
        #pragma unroll
        for (int m = 0; m < 2; ++m)
            #pragma unroll
            for (int k2 = 0; k2 < 2; ++k2) {
                int row = (ah * 2 + m) * 16 + l15; row = row > 48 ? 48 : row;
                pf[m][k2] = *(const bf16x8*)(smem + pbase + row * 144 + ((k2 * 32 + sub * 8) << 1));
            }
        #pragma unroll
        for (int nt = 0; nt < 4; ++nt)
            #pragma unroll
            for (int k2 = 0; k2 < 2; ++k2)
                vf[nt][k2] = *(const bf16x8*)(smem + OFF_V + ((((h * 4 + nt) << 1) + k2) << 10) + lane * 16);

        f32x4 oc[2][4];
        #pragma unroll
        for (int m = 0; m < 2; ++m)
            #pragma unroll
            for (int nt = 0; nt < 4; ++nt) oc[m][nt] = z4;
        #pragma unroll
        for (int k2 = 0; k2 < 2; ++k2)
            #pragma unroll
            for (int m = 0; m < 2; ++m)
                #pragma unroll
                for (int nt = 0; nt < 4; ++nt)
                    oc[m][nt] = mfma16(pf[m][k2], vf[nt][k2], oc[m][nt]);
        #pragma unroll
        for (int m = 0; m < 2; ++m)
            #pragma unroll
            for (int nt = 0; nt < 4; ++nt)
                #pragma unroll
                for (int r = 0; r < 4; ++r) {
                    int t = (ah * 2 + m) * 16 + sub * 4 + r;
                    int c = h * 64 + nt * 16 + l15;
                    *(unsigned short*)(smem + frOff(OFF_OF, t, c)) = f2bf(oc[m][nt][r]);
                }
    }
    __syncthreads();   // 5

    // ---- P6: proj + residual RMW into persistent sX ----
    float* sW = sX;
    {
        bf16x8 pbF1[8];
        #pragma unroll
        for (int kt = 0; kt < 8; ++kt)
            pbF1[kt] = *(const bf16x8*)(ws + (size_t)(((WS_PROJ_BLK + (wid * 2 + 1) * 8 + kt)) << 10) + lane * 16);

        bf16x8 aF[4][8];
        #pragma unroll
        for (int mt = 0; mt < 4; ++mt)
            #pragma unroll
            for (int kt = 0; kt < 8; ++kt)
                aF[mt][kt] = *(const bf16x8*)(smem + OFF_OF + ((mt * 8 + kt) << 10) + lane * 16);

        auto proj_epi = [&](int ntg, const f32x4 (&acc)[4]) {
            const int c = ntg * 16 + l15;
            const float bias = proj_b[c];
            #pragma unroll
            for (int mt = 0; mt < 4; ++mt)
                #pragma unroll
                for (int r = 0; r < 4; ++r) {
                    int t = mt * 16 + sub * 4 + r;
                    if (t < TOK) sW[t * SX_ST + c] += acc[mt][r] + bias;
                }
        };

        {
            f32x4 acc[4] = {z4, z4, z4, z4};
            #pragma unroll
            for (int kt = 0; kt < 8; ++kt)
                #pragma unroll
                for (int mt = 0; mt < 4; ++mt)
                    acc[mt] = mfma16(aF[mt][kt], pbF0[kt], acc[mt]);
            proj_epi(wid * 2, acc);
        }
        {
            f32x4 acc[4] = {z4, z4, z4, z4};
            #pragma unroll
            for (int kt = 0; kt < 8; ++kt)
                #pragma unroll
                for (int mt = 0; mt < 4; ++mt)
                    acc[mt] = mfma16(aF[mt][kt], pbF1[kt], acc[mt]);
            proj_epi(wid * 2 + 1, acc);
        }
    }
    __syncthreads();   // 6

    // ---- P7: LN2 stats ----
    for (int t = wid; t < TOK; t += 8) {
        const float4 v = *(const float4*)&sW[t * SX_ST + lane * 4];
        float s1 = v.x + v.y + v.z + v.w;
        float s2 = v.x * v.x + v.y * v.y + v.z * v.z + v.w * v.w;
        #pragma unroll
        for (int off = 32; off > 0; off >>= 1) {
            s1 += __shfl_xor(s1, off);
            s2 += __shfl_xor(s2, off);
        }
        if (lane == 0) {
            float m = s1 * (1.f / 256.f);
            float var = s2 * (1.f / 256.f) - m * m;
            sM[t] = m; sR[t] = rsqrtf(var + 1e-5f);
        }
    }
    __syncthreads();   // 7

    // ---- P8: LN2 normalize -> n2F ----
    for (int e = tid; e < 2048; e += NTHR) {
        int t = e & 63, cb = e >> 6;
        char* dst = smem + OFF_AF + (((t >> 4) * 8 + (cb >> 2)) << 10)
                  + (((((cb & 3) << 4) | (t & 15))) << 4);
        if (t < TOK) {
            const float* xr = sW + t * SX_ST + cb * 8;
            float4 xa = *(const float4*)xr;
            float4 xb = *(const float4*)(xr + 4);
            float m = sM[t], rs = sR[t];
            int c = cb * 8;
            u16x8 o;
            o[0] = f2bf((xa.x - m) * rs * sG2[c + 0] + sB2[c + 0]);
            o[1] = f2bf((xa.y - m) * rs * sG2[c + 1] + sB2[c + 1]);
            o[2] = f2bf((xa.z - m) * rs * sG2[c + 2] + sB2[c + 2]);
            o[3] = f2bf((xa.w - m) * rs * sG2[c + 3] + sB2[c + 3]);
            o[4] = f2bf((xb.x - m) * rs * sG2[c + 4] + sB2[c + 4]);
            o[5] = f2bf((xb.y - m) * rs * sG2[c + 5] + sB2[c + 5]);
            o[6] = f2bf((xb.z - m) * rs * sG2[c + 6] + sB2[c + 6]);
            o[7] = f2bf((xb.w - m) * rs * sG2[c + 7] + sB2[c + 7]);
            *(u16x8*)dst = o;
        } else {
            u16x8 z = {0, 0, 0, 0, 0, 0, 0, 0};
            *(u16x8*)dst = z;
        }
    }
    __syncthreads();   // 8

    // ---- P9: MLP in two K-halves; mt-split fragment loads cap register pressure ----
    {
        f32x4 acc2[2][4];
        #pragma unroll
        for (int i = 0; i < 2; ++i)
            #pragma unroll
            for (int mt = 0; mt < 4; ++mt) acc2[i][mt] = z4;

        for (int half = 0; half < 2; ++half) {
            // MLP1: both weight tiles resident; fragments loaded per mt-half
            {
                bf16x8 bF0[8], bF1[8];
                #pragma unroll
                for (int kt = 0; kt < 8; ++kt) {
                    bF0[kt] = *(const bf16x8*)(ws + (size_t)(((WS_W1_BLK + (half * 16 + wid * 2) * 8 + kt)) << 10) + lane * 16);
                    bF1[kt] = *(const bf16x8*)(ws + (size_t)(((WS_W1_BLK + (half * 16 + wid * 2 + 1) * 8 + kt)) << 10) + lane * 16);
                }

                #pragma unroll
                for (int mh = 0; mh < 2; ++mh) {
                    bf16x8 nf[2][8];
                    #pragma unroll
                    for (int mm = 0; mm < 2; ++mm)
                        #pragma unroll
                        for (int kt = 0; kt < 8; ++kt)
                            nf[mm][kt] = *(const bf16x8*)(smem + OFF_AF + (((mh * 2 + mm) * 8 + kt) << 10) + lane * 16);

                    f32x4 a0[2] = {z4, z4}, a1[2] = {z4, z4};
                    #pragma unroll
                    for (int kt = 0; kt < 8; ++kt)
                        #pragma unroll
                        for (int mm = 0; mm < 2; ++mm) {
                            a0[mm] = mfma16(nf[mm][kt], bF0[kt], a0[mm]);
                            a1[mm] = mfma16(nf[mm][kt], bF1[kt], a1[mm]);
                        }

                    #pragma unroll
                    for (int tile = 0; tile < 2; ++tile) {
                        const int ntg = wid * 2 + tile;
                        const int chm = ntg * 16 + l15;
                        const float bias = b1[half * 256 + chm];
                        #pragma unroll
                        for (int mm = 0; mm < 2; ++mm)
                            #pragma unroll
                            for (int r = 0; r < 4; ++r) {
                                int t = (mh * 2 + mm) * 16 + sub * 4 + r;
                                if (t < TOK) {
                                    float v = (tile ? a1[mm][r] : a0[mm][r]) + bias;
                                    float u = v * (1.5957691216f + 0.07135481627f * v * v);
                                    float g = v / (1.f + __expf(-u));
                                    *(unsigned short*)(smem + frOff(OFF_HM, t, chm)) = f2bf(g);
                                }
                            }
                    }
                }
            }
            __syncthreads();   // HM ready

            // MLP2 partial: both weight tiles resident; fragments per mt-half
            {
                bf16x8 bF0[8], bF1[8];
                #pragma unroll
                for (int kt = 0; kt < 8; ++kt) {
                    bF0[kt] = *(const bf16x8*)(ws + (size_t)(((WS_W2_BLK + (wid * 2 + 0) * 16 + half * 8 + kt)) << 10) + lane * 16);
                    bF1[kt] = *(const bf16x8*)(ws + (size_t)(((WS_W2_BLK + (wid * 2 + 1) * 16 + half * 8 + kt)) << 10) + lane * 16);
                }
                #pragma unroll
                for (int mh = 0; mh < 2; ++mh) {
                    bf16x8 hf[2][8];
                    #pragma unroll
                    for (int mm = 0; mm < 2; ++mm)
                        #pragma unroll
                        for (int kt = 0; kt < 8; ++kt)
                            hf[mm][kt] = *(const bf16x8*)(smem + OFF_HM + (((mh * 2 + mm) * 8 + kt) << 10) + lane * 16);
                    #pragma unroll
                    for (int kt = 0; kt < 8; ++kt)
                        #pragma unroll
                        for (int mm = 0; mm < 2; ++mm) {
                            acc2[0][mh * 2 + mm] = mfma16(hf[mm][kt], bF0[kt], acc2[0][mh * 2 + mm]);
                            acc2[1][mh * 2 + mm] = mfma16(hf[mm][kt], bF1[kt], acc2[1][mh * 2 + mm]);
                        }
                }
            }
            __syncthreads();   // HM reads done
        }

        // epilogue: win2 += mlp2 + b2
        #pragma unroll
        for (int i = 0; i < 2; ++i) {
            const int c = (wid * 2 + i) * 16 + l15;
            const float bias = b2[c];
            #pragma unroll
            for (int mt = 0; mt < 4; ++mt)
                #pragma unroll
                for (int r = 0; r < 4; ++r) {
                    int t = mt * 16 + sub * 4 + r;
                    if (t < TOK) sW[t * SX_ST + c] += acc2[i][mt][r] + bias;
                }
        }
    }
    __syncthreads();   // final

    // ---- P10: window-reverse store (lane = spatial token) ----
    if (lane < TOK) {
        float* ys = y + xbase + (size_t)(row0 + li7) * IMG + (col0 + lj7);
        const float* src = sW + lane * SX_ST;
        #pragma unroll 8
        for (int c = wid; c < CH; c += 8)
            ys[(size_t)c * (IMG * IMG)] = src[c];
    }
}

extern "C" void kernel_launch(void* const* d_in, const int* in_sizes, int n_in,
                              void* d_out, int out_size, void* d_ws, size_t ws_size,
                              hipStream_t stream) {
    const float* x      = (const float*)d_in[0];
    const float* ln1_g  = (const float*)d_in[1];
    const float* ln1_b  = (const float*)d_in[2];
    const float* qkv_w  = (const float*)d_in[3];
    const float* qkv_b  = (const float*)d_in[4];
    const float* proj_w = (const float*)d_in[5];
    const float* proj_b = (const float*)d_in[6];
    const float* ln2_g  = (const float*)d_in[7];
    const float* ln2_b  = (const float*)d_in[8];
    const float* w1     = (const float*)d_in[9];
    const float* b1     = (const float*)d_in[10];
    const float* w2     = (const float*)d_in[11];
    const float* b2     = (const float*)d_in[12];

    hipLaunchKernelGGL(prepack, dim3(1024), dim3(64), 0, stream,
                       qkv_w, proj_w, w1, w2, (char*)d_ws);
    hipLaunchKernelGGL(swin_block, dim3(NWIN), dim3(NTHR), 0, stream,
                       x, ln1_g, ln1_b, qkv_b, proj_b, ln2_g, ln2_b, b1, b2,
                       (const char*)d_ws, (float*)d_out);
}

// Round 15
// 683.878 us; speedup vs baseline: 1.1933x; 1.0716x over previous
//
#include <hip/hip_runtime.h>
#include <hip/hip_bf16.h>

typedef __bf16 bf16x8 __attribute__((ext_vector_type(8)));
typedef float  f32x4  __attribute__((ext_vector_type(4)));
typedef unsigned short u16x8 __attribute__((ext_vector_type(8)));

#define CH    256
#define IMG   112
#define WSZ   7
#define TOK   49
#define NWIN  4096
#define HID   512
#define NTHR  512

#define SX_ST 260          // f32 row stride for sX (permanent window buffer)

// ---- LDS arena (byte offsets), time-multiplexed ----
#define OFF_AF   51200
#define OFF_V    51200
#define OFF_Q    83968
#define OFF_P    83968
#define PSZ      7168
#define OFF_HM   83968
#define OFF_K    116736
#define OFF_OF   116736
#define OFF_MR   149504     // sM[64], sR[64]
#define OFF_PRM  150016     // sG1,sB1,sG2,sB2 (each 256 f32)
#define OFF_PART 154112     // float2[49*8] LN partials
#define SMEM_SZ  157248

// ---- d_ws layout: bf16 B-fragment blocks, 1KB each ----
#define WS_PROJ_BLK 384
#define WS_W1_BLK   512
#define WS_W2_BLK   768

__device__ __forceinline__ unsigned short f2bf(float f) {
    __bf16 h = (__bf16)f;
    return __builtin_bit_cast(unsigned short, h);
}

__device__ __forceinline__ f32x4 mfma16(bf16x8 a, bf16x8 b, f32x4 c) {
    return __builtin_amdgcn_mfma_f32_16x16x32_bf16(a, b, c, 0, 0, 0);
}

__device__ __forceinline__ int frOff(int base, int t, int c) {
    return base + (((t >> 4) * 8 + (c >> 5)) << 10)
                + (((((c >> 3) & 3) << 4) | (t & 15)) << 4)
                + ((c & 7) << 1);
}
__device__ __forceinline__ int frOffT(int base, int c, int t) {
    return base + ((((c >> 4) << 1) + (t >> 5)) << 10)
                + (((((t >> 3) & 3) << 4) | (c & 15)) << 4)
                + ((t & 7) << 1);
}

// ---------------- prepack: fp32 weights -> bf16 B-fragment blocks in d_ws ----------------
extern "C" __global__ __launch_bounds__(64)
void prepack(const float* __restrict__ qkv_w, const float* __restrict__ proj_w,
             const float* __restrict__ w1, const float* __restrict__ w2,
             char* __restrict__ ws)
{
    const int blk = blockIdx.x, l = threadIdx.x;
    const float* W; int nt, kt, ncols;
    if (blk < WS_PROJ_BLK)      { W = qkv_w;  int i = blk;               nt = i >> 3; kt = i & 7;  ncols = 768; }
    else if (blk < WS_W1_BLK)   { W = proj_w; int i = blk - WS_PROJ_BLK; nt = i >> 3; kt = i & 7;  ncols = 256; }
    else if (blk < WS_W2_BLK)   { W = w1;     int i = blk - WS_W1_BLK;   nt = i >> 3; kt = i & 7;  ncols = 512; }
    else                        { W = w2;     int i = blk - WS_W2_BLK;   nt = i >> 4; kt = i & 15; ncols = 256; }
    const int n  = nt * 16 + (l & 15);
    const int k0 = kt * 32 + (l >> 4) * 8;
    u16x8 o;
    #pragma unroll
    for (int j = 0; j < 8; ++j) o[j] = f2bf(W[(size_t)(k0 + j) * ncols + n]);
    *(u16x8*)(ws + (size_t)blk * 1024 + l * 16) = o;
}

// ---------------- main fused block: 8 waves, XCD swizzle, fused LN1+LN2 stats ----------------
extern "C" __global__ __launch_bounds__(NTHR, 1)
void swin_block(const float* __restrict__ x,
                const float* __restrict__ ln1_g, const float* __restrict__ ln1_b,
                const float* __restrict__ qkv_b,
                const float* __restrict__ proj_b,
                const float* __restrict__ ln2_g, const float* __restrict__ ln2_b,
                const float* __restrict__ b1, const float* __restrict__ b2,
                const char* __restrict__ ws,
                float* __restrict__ y)
{
    __shared__ __align__(16) char smem[SMEM_SZ];
    float*  sX = (float*)(smem + 0);          // persistent; becomes win2 in place
    float*  sM = (float*)(smem + OFF_MR);
    float*  sR = sM + 64;
    float*  sG1 = (float*)(smem + OFF_PRM);
    float*  sB1 = sG1 + 256;
    float*  sG2 = sB1 + 256;
    float*  sB2 = sG2 + 256;
    float2* sPart = (float2*)(smem + OFF_PART);

    const int tid  = threadIdx.x;
    const int wid  = tid >> 6;       // 0..7
    const int lane = tid & 63;
    const int sub  = lane >> 4;
    const int l15  = lane & 15;
    const int li7  = lane / 7;       // spatial row (lane<49)
    const int lj7  = lane - li7 * 7; // spatial col

    // XCD-aware swizzle: each XCD gets a contiguous run of 512 windows (2 images)
    const int bid = blockIdx.x;
    const int n  = (bid & 7) * (NWIN / 8) + (bid >> 3);
    const int b  = n >> 8;
    const int wh = (n >> 4) & 15;
    const int ww = n & 15;
    const int row0 = wh * WSZ, col0 = ww * WSZ;
    const size_t xbase = (size_t)b * CH * IMG * IMG;

    const f32x4 z4 = {0.f, 0.f, 0.f, 0.f};

    bf16x8 pbF0[8];      // proj tile-0 weights (filled in P4, consumed in P6)

    // ---- P0: stage x -> sX with fused LN1 partial sums ----
    {
        float ps1 = 0.f, ps2 = 0.f;
        if (lane < TOK) {
            const float* xs = x + xbase + (size_t)(row0 + li7) * IMG + (col0 + lj7);
            float* dst = sX + lane * SX_ST;
            #pragma unroll 8
            for (int c = wid; c < CH; c += 8) {
                float v = xs[(size_t)c * (IMG * IMG)];
                dst[c] = v;
                ps1 += v; ps2 += v * v;
            }
        }
        int t2 = tid & 255;
        if (tid < 256) { sG1[t2] = ln1_g[t2]; sB1[t2] = ln1_b[t2]; }
        else           { sG2[t2] = ln2_g[t2]; sB2[t2] = ln2_b[t2]; }
        if (lane < TOK) sPart[lane * 8 + wid] = make_float2(ps1, ps2);
    }
    __syncthreads();   // 1

    // ---- P1: LN1 finalize (tiny) ----
    if (tid < TOK) {
        float s1 = 0.f, s2 = 0.f;
        #pragma unroll
        for (int w = 0; w < 8; ++w) {
            float2 q = sPart[tid * 8 + w];
            s1 += q.x; s2 += q.y;
        }
        float m = s1 * (1.f / 256.f);
        float var = s2 * (1.f / 256.f) - m * m;
        sM[tid] = m; sR[tid] = rsqrtf(var + 1e-5f);
    }
    __syncthreads();   // 2

    // prefetch first QKV B-batch (latency hides under P2; drains at barrier 3)
    bf16x8 bA[8], bB[8];
    #pragma unroll
    for (int kt = 0; kt < 8; ++kt)
        bA[kt] = *(const bf16x8*)(ws + (size_t)(((wid * 6) * 8 + kt) << 10) + lane * 16);

    // ---- P2: normalize -> n1F fragment blocks; zero pad rows ----
    for (int e = tid; e < 2048; e += NTHR) {
        int t = e & 63, cb = e >> 6;
        char* dst = smem + OFF_AF + (((t >> 4) * 8 + (cb >> 2)) << 10)
                  + (((((cb & 3) << 4) | (t & 15))) << 4);
        if (t < TOK) {
            const float* xr = sX + t * SX_ST + cb * 8;
            float4 xa = *(const float4*)xr;
            float4 xb = *(const float4*)(xr + 4);
            float m = sM[t], rs = sR[t];
            int c = cb * 8;
            u16x8 o;
            o[0] = f2bf((xa.x - m) * rs * sG1[c + 0] + sB1[c + 0]);
            o[1] = f2bf((xa.y - m) * rs * sG1[c + 1] + sB1[c + 1]);
            o[2] = f2bf((xa.z - m) * rs * sG1[c + 2] + sB1[c + 2]);
            o[3] = f2bf((xa.w - m) * rs * sG1[c + 3] + sB1[c + 3]);
            o[4] = f2bf((xb.x - m) * rs * sG1[c + 4] + sB1[c + 4]);
            o[5] = f2bf((xb.y - m) * rs * sG1[c + 5] + sB1[c + 5]);
            o[6] = f2bf((xb.z - m) * rs * sG1[c + 6] + sB1[c + 6]);
            o[7] = f2bf((xb.w - m) * rs * sG1[c + 7] + sB1[c + 7]);
            *(u16x8*)dst = o;
        } else {
            u16x8 z = {0, 0, 0, 0, 0, 0, 0, 0};
            *(u16x8*)dst = z;
        }
    }
    __syncthreads();   // 3

    // ---- P3: QKV GEMM (M=64,N=768,K=256); V frags overwrite n1F region after 3b ----
    {
        bf16x8 aF[4][8];
        #pragma unroll
        for (int mt = 0; mt < 4; ++mt)
            #pragma unroll
            for (int kt = 0; kt < 8; ++kt)
                aF[mt][kt] = *(const bf16x8*)(smem + OFF_AF + ((mt * 8 + kt) << 10) + lane * 16);
        __syncthreads();   // 3b: all waves hold n1F in regs; V may overwrite region

        auto qkv_epi = [&](int ntg, const f32x4 (&acc)[4]) {
            const float bias = qkv_b[ntg * 16 + l15];
            const int m3 = ntg >> 4;              // 0=Q 1=K 2=V
            const int c = (ntg & 15) * 16 + l15;
            if (m3 == 2) {
                #pragma unroll
                for (int mt = 0; mt < 4; ++mt)
                    #pragma unroll
                    for (int r = 0; r < 4; ++r) {
                        int t = mt * 16 + sub * 4 + r;
                        *(unsigned short*)(smem + frOffT(OFF_V, c, t)) = f2bf(acc[mt][r] + bias);
                    }
            } else if (m3 == 1) {
                #pragma unroll
                for (int mt = 0; mt < 4; ++mt)
                    #pragma unroll
                    for (int r = 0; r < 4; ++r) {
                        int t = mt * 16 + sub * 4 + r;
                        *(unsigned short*)(smem + frOff(OFF_K, t, c)) = f2bf(acc[mt][r] + bias);
                    }
            } else {
                #pragma unroll
                for (int mt = 0; mt < 4; ++mt)
                    #pragma unroll
                    for (int r = 0; r < 4; ++r) {
                        int t = mt * 16 + sub * 4 + r;
                        *(unsigned short*)(smem + frOff(OFF_Q, t, c)) = f2bf((acc[mt][r] + bias) * 0.125f);
                    }
            }
        };

        for (int i = 0; i < 6; i += 2) {
            const int n0 = wid * 6 + i;
            #pragma unroll
            for (int kt = 0; kt < 8; ++kt)
                bB[kt] = *(const bf16x8*)(ws + (size_t)(((n0 + 1) * 8 + kt) << 10) + lane * 16);
            {
                f32x4 acc[4] = {z4, z4, z4, z4};
                #pragma unroll
                for (int kt = 0; kt < 8; ++kt)
                    #pragma unroll
                    for (int mt = 0; mt < 4; ++mt)
                        acc[mt] = mfma16(aF[mt][kt], bA[kt], acc[mt]);
                qkv_epi(n0, acc);
            }
            if (i + 2 < 6) {
                #pragma unroll
                for (int kt = 0; kt < 8; ++kt)
                    bA[kt] = *(const bf16x8*)(ws + (size_t)(((n0 + 2) * 8 + kt) << 10) + lane * 16);
            }
            {
                f32x4 acc[4] = {z4, z4, z4, z4};
                #pragma unroll
                for (int kt = 0; kt < 8; ++kt)
                    #pragma unroll
                    for (int mt = 0; mt < 4; ++mt)
                        acc[mt] = mfma16(aF[mt][kt], bB[kt], acc[mt]);
                qkv_epi(n0 + 1, acc);
            }
        }
    }
    __syncthreads();   // 4

    // ---- P4: attention; wave = (head h = wid>>1, m-half ah = wid&1) ----
    {
        const int h  = wid >> 1;
        const int ah = wid & 1;
        f32x4 sc[2][4];
        #pragma unroll
        for (int m = 0; m < 2; ++m)
            #pragma unroll
            for (int nt = 0; nt < 4; ++nt) sc[m][nt] = z4;

        {
            bf16x8 qf[2][2], kf[4][2];
            #pragma unroll
            for (int m = 0; m < 2; ++m)
                #pragma unroll
                for (int k2 = 0; k2 < 2; ++k2)
                    qf[m][k2] = *(const bf16x8*)(smem + OFF_Q + (((ah * 2 + m) * 8 + h * 2 + k2) << 10) + lane * 16);
            #pragma unroll
            for (int nt = 0; nt < 4; ++nt)
                #pragma unroll
                for (int k2 = 0; k2 < 2; ++k2)
                    kf[nt][k2] = *(const bf16x8*)(smem + OFF_K + ((nt * 8 + h * 2 + k2) << 10) + lane * 16);
            #pragma unroll
            for (int k2 = 0; k2 < 2; ++k2)
                #pragma unroll
                for (int m = 0; m < 2; ++m)
                    #pragma unroll
                    for (int nt = 0; nt < 4; ++nt)
                        sc[m][nt] = mfma16(qf[m][k2], kf[nt][k2], sc[m][nt]);
        }
        __syncthreads();   // 4a: Q/K reads drained (P may overwrite Q region; OF may overwrite K region)

        // cross-barrier prefetch: proj tile-0 weights (consumed in P6; hides under softmax/PV)
        #pragma unroll
        for (int kt = 0; kt < 8; ++kt)
            pbF0[kt] = *(const bf16x8*)(ws + (size_t)(((WS_PROJ_BLK + (wid * 2) * 8 + kt)) << 10) + lane * 16);

        const int pbase = OFF_P + h * PSZ;
        #pragma unroll
        for (int m = 0; m < 2; ++m) {
            #pragma unroll
            for (int r = 0; r < 4; ++r) {
                const int t = (ah * 2 + m) * 16 + sub * 4 + r;
                float v0 = sc[m][0][r];
                float v1 = sc[m][1][r];
                float v2 = sc[m][2][r];
                float v3 = (l15 == 0) ? sc[m][3][r] : -1e30f;
                float mx = fmaxf(fmaxf(v0, v1), fmaxf(v2, v3));
                mx = fmaxf(mx, __shfl_xor(mx, 1));
                mx = fmaxf(mx, __shfl_xor(mx, 2));
                mx = fmaxf(mx, __shfl_xor(mx, 4));
                mx = fmaxf(mx, __shfl_xor(mx, 8));
                float e0 = __expf(v0 - mx), e1 = __expf(v1 - mx);
                float e2 = __expf(v2 - mx), e3 = __expf(v3 - mx);
                float s = e0 + e1 + e2 + e3;
                s += __shfl_xor(s, 1);
                s += __shfl_xor(s, 2);
                s += __shfl_xor(s, 4);
                s += __shfl_xor(s, 8);
                float inv = 1.f / s;
                if (t < TOK) {
                    unsigned short* pr = (unsigned short*)(smem + pbase + t * 144);
                    pr[l15]      = f2bf(e0 * inv);
                    pr[16 + l15] = f2bf(e1 * inv);
                    pr[32 + l15] = f2bf(e2 * inv);
                    pr[48 + l15] = f2bf(e3 * inv);
                }
            }
        }

        // PV: O_h rows of this m-half (P rows wave-local: same-wave write->read)
        bf16x8 pf[2][2], vf[4][2];
        #pragma unroll
        for (int m = 0; m < 2; ++m)
            #pragma unroll
            for (int k2 = 0; k2 < 2; ++k2) {
                int row = (ah * 2 + m) * 16 + l15; row = row > 48 ? 48 : row;
                pf[m][k2] = *(const bf16x8*)(smem + pbase + row * 144 + ((k2 * 32 + sub * 8) << 1));
            }
        #pragma unroll
        for (int nt = 0; nt < 4; ++nt)
            #pragma unroll
            for (int k2 = 0; k2 < 2; ++k2)
                vf[nt][k2] = *(const bf16x8*)(smem + OFF_V + ((((h * 4 + nt) << 1) + k2) << 10) + lane * 16);

        f32x4 oc[2][4];
        #pragma unroll
        for (int m = 0; m < 2; ++m)
            #pragma unroll
            for (int nt = 0; nt < 4; ++nt) oc[m][nt] = z4;
        #pragma unroll
        for (int k2 = 0; k2 < 2; ++k2)
            #pragma unroll
            for (int m = 0; m < 2; ++m)
                #pragma unroll
                for (int nt = 0; nt < 4; ++nt)
                    oc[m][nt] = mfma16(pf[m][k2], vf[nt][k2], oc[m][nt]);
        #pragma unroll
        for (int m = 0; m < 2; ++m)
            #pragma unroll
            for (int nt = 0; nt < 4; ++nt)
                #pragma unroll
                for (int r = 0; r < 4; ++r) {
                    int t = (ah * 2 + m) * 16 + sub * 4 + r;
                    int c = h * 64 + nt * 16 + l15;
                    *(unsigned short*)(smem + frOff(OFF_OF, t, c)) = f2bf(oc[m][nt][r]);
                }
    }
    __syncthreads();   // 5

    // ---- P6: proj + residual RMW into persistent sX, LN2 partials fused ----
    float* sW = sX;
    {
        bf16x8 pbF1[8];
        #pragma unroll
        for (int kt = 0; kt < 8; ++kt)
            pbF1[kt] = *(const bf16x8*)(ws + (size_t)(((WS_PROJ_BLK + (wid * 2 + 1) * 8 + kt)) << 10) + lane * 16);

        bf16x8 aF[4][8];
        #pragma unroll
        for (int mt = 0; mt < 4; ++mt)
            #pragma unroll
            for (int kt = 0; kt < 8; ++kt)
                aF[mt][kt] = *(const bf16x8*)(smem + OFF_OF + ((mt * 8 + kt) << 10) + lane * 16);

        // epi: RMW sW, inline per-t reduce over this wave's 16 channels, accumulate sPart
        auto proj_epi = [&](int ntg, const f32x4 (&acc)[4], bool first) {
            const int c = ntg * 16 + l15;
            const float bias = proj_b[c];
            #pragma unroll
            for (int mt = 0; mt < 4; ++mt)
                #pragma unroll
                for (int r = 0; r < 4; ++r) {
                    int t = mt * 16 + sub * 4 + r;
                    if (t < TOK) {
                        float w = sW[t * SX_ST + c] + acc[mt][r] + bias;
                        sW[t * SX_ST + c] = w;
                        float a = w, bb = w * w;
                        a += __shfl_xor(a, 1); bb += __shfl_xor(bb, 1);
                        a += __shfl_xor(a, 2); bb += __shfl_xor(bb, 2);
                        a += __shfl_xor(a, 4); bb += __shfl_xor(bb, 4);
                        a += __shfl_xor(a, 8); bb += __shfl_xor(bb, 8);
                        if (l15 == 0) {
                            if (first) {
                                sPart[t * 8 + wid] = make_float2(a, bb);
                            } else {
                                float2 q = sPart[t * 8 + wid];
                                sPart[t * 8 + wid] = make_float2(q.x + a, q.y + bb);
                            }
                        }
                    }
                }
        };

        {
            f32x4 acc[4] = {z4, z4, z4, z4};
            #pragma unroll
            for (int kt = 0; kt < 8; ++kt)
                #pragma unroll
                for (int mt = 0; mt < 4; ++mt)
                    acc[mt] = mfma16(aF[mt][kt], pbF0[kt], acc[mt]);
            proj_epi(wid * 2, acc, true);
        }
        {
            f32x4 acc[4] = {z4, z4, z4, z4};
            #pragma unroll
            for (int kt = 0; kt < 8; ++kt)
                #pragma unroll
                for (int mt = 0; mt < 4; ++mt)
                    acc[mt] = mfma16(aF[mt][kt], pbF1[kt], acc[mt]);
            proj_epi(wid * 2 + 1, acc, false);
        }
    }
    __syncthreads();   // 6

    // ---- P7: LN2 finalize (tiny) ----
    if (tid < TOK) {
        float s1 = 0.f, s2 = 0.f;
        #pragma unroll
        for (int w = 0; w < 8; ++w) {
            float2 q = sPart[tid * 8 + w];
            s1 += q.x; s2 += q.y;
        }
        float m = s1 * (1.f / 256.f);
        float var = s2 * (1.f / 256.f) - m * m;
        sM[tid] = m; sR[tid] = rsqrtf(var + 1e-5f);
    }
    __syncthreads();   // 7

    // ---- P8: LN2 normalize -> n2F ----
    for (int e = tid; e < 2048; e += NTHR) {
        int t = e & 63, cb = e >> 6;
        char* dst = smem + OFF_AF + (((t >> 4) * 8 + (cb >> 2)) << 10)
                  + (((((cb & 3) << 4) | (t & 15))) << 4);
        if (t < TOK) {
            const float* xr = sW + t * SX_ST + cb * 8;
            float4 xa = *(const float4*)xr;
            float4 xb = *(const float4*)(xr + 4);
            float m = sM[t], rs = sR[t];
            int c = cb * 8;
            u16x8 o;
            o[0] = f2bf((xa.x - m) * rs * sG2[c + 0] + sB2[c + 0]);
            o[1] = f2bf((xa.y - m) * rs * sG2[c + 1] + sB2[c + 1]);
            o[2] = f2bf((xa.z - m) * rs * sG2[c + 2] + sB2[c + 2]);
            o[3] = f2bf((xa.w - m) * rs * sG2[c + 3] + sB2[c + 3]);
            o[4] = f2bf((xb.x - m) * rs * sG2[c + 4] + sB2[c + 4]);
            o[5] = f2bf((xb.y - m) * rs * sG2[c + 5] + sB2[c + 5]);
            o[6] = f2bf((xb.z - m) * rs * sG2[c + 6] + sB2[c + 6]);
            o[7] = f2bf((xb.w - m) * rs * sG2[c + 7] + sB2[c + 7]);
            *(u16x8*)dst = o;
        } else {
            u16x8 z = {0, 0, 0, 0, 0, 0, 0, 0};
            *(u16x8*)dst = z;
        }
    }
    __syncthreads();   // 8

    // ---- P9: MLP in two K-halves; mt-split fragment loads cap register pressure ----
    {
        f32x4 acc2[2][4];
        #pragma unroll
        for (int i = 0; i < 2; ++i)
            #pragma unroll
            for (int mt = 0; mt < 4; ++mt) acc2[i][mt] = z4;

        for (int half = 0; half < 2; ++half) {
            // MLP1: both weight tiles resident; fragments loaded per mt-half
            {
                bf16x8 bF0[8], bF1[8];
                #pragma unroll
                for (int kt = 0; kt < 8; ++kt) {
                    bF0[kt] = *(const bf16x8*)(ws + (size_t)(((WS_W1_BLK + (half * 16 + wid * 2) * 8 + kt)) << 10) + lane * 16);
                    bF1[kt] = *(const bf16x8*)(ws + (size_t)(((WS_W1_BLK + (half * 16 + wid * 2 + 1) * 8 + kt)) << 10) + lane * 16);
                }

                #pragma unroll
                for (int mh = 0; mh < 2; ++mh) {
                    bf16x8 nf[2][8];
                    #pragma unroll
                    for (int mm = 0; mm < 2; ++mm)
                        #pragma unroll
                        for (int kt = 0; kt < 8; ++kt)
                            nf[mm][kt] = *(const bf16x8*)(smem + OFF_AF + (((mh * 2 + mm) * 8 + kt) << 10) + lane * 16);

                    f32x4 a0[2] = {z4, z4}, a1[2] = {z4, z4};
                    #pragma unroll
                    for (int kt = 0; kt < 8; ++kt)
                        #pragma unroll
                        for (int mm = 0; mm < 2; ++mm) {
                            a0[mm] = mfma16(nf[mm][kt], bF0[kt], a0[mm]);
                            a1[mm] = mfma16(nf[mm][kt], bF1[kt], a1[mm]);
                        }

                    #pragma unroll
                    for (int tile = 0; tile < 2; ++tile) {
                        const int ntg = wid * 2 + tile;
                        const int chm = ntg * 16 + l15;
                        const float bias = b1[half * 256 + chm];
                        #pragma unroll
                        for (int mm = 0; mm < 2; ++mm)
                            #pragma unroll
                            for (int r = 0; r < 4; ++r) {
                                int t = (mh * 2 + mm) * 16 + sub * 4 + r;
                                if (t < TOK) {
                                    float v = (tile ? a1[mm][r] : a0[mm][r]) + bias;
                                    float u = v * (1.5957691216f + 0.07135481627f * v * v);
                                    float g = v / (1.f + __expf(-u));
                                    *(unsigned short*)(smem + frOff(OFF_HM, t, chm)) = f2bf(g);
                                }
                            }
                    }
                }
            }
            __syncthreads();   // HM ready

            // MLP2 partial: both weight tiles resident; fragments per mt-half
            {
                bf16x8 bF0[8], bF1[8];
                #pragma unroll
                for (int kt = 0; kt < 8; ++kt) {
                    bF0[kt] = *(const bf16x8*)(ws + (size_t)(((WS_W2_BLK + (wid * 2 + 0) * 16 + half * 8 + kt)) << 10) + lane * 16);
                    bF1[kt] = *(const bf16x8*)(ws + (size_t)(((WS_W2_BLK + (wid * 2 + 1) * 16 + half * 8 + kt)) << 10) + lane * 16);
                }
                #pragma unroll
                for (int mh = 0; mh < 2; ++mh) {
                    bf16x8 hf[2][8];
                    #pragma unroll
                    for (int mm = 0; mm < 2; ++mm)
                        #pragma unroll
                        for (int kt = 0; kt < 8; ++kt)
                            hf[mm][kt] = *(const bf16x8*)(smem + OFF_HM + (((mh * 2 + mm) * 8 + kt) << 10) + lane * 16);
                    #pragma unroll
                    for (int kt = 0; kt < 8; ++kt)
                        #pragma unroll
                        for (int mm = 0; mm < 2; ++mm) {
                            acc2[0][mh * 2 + mm] = mfma16(hf[mm][kt], bF0[kt], acc2[0][mh * 2 + mm]);
                            acc2[1][mh * 2 + mm] = mfma16(hf[mm][kt], bF1[kt], acc2[1][mh * 2 + mm]);
                        }
                }
            }
            __syncthreads();   // HM reads done
        }

        // epilogue: win2 += mlp2 + b2
        #pragma unroll
        for (int i = 0; i < 2; ++i) {
            const int c = (wid * 2 + i) * 16 + l15;
            const float bias = b2[c];
            #pragma unroll
            for (int mt = 0; mt < 4; ++mt)
                #pragma unroll
                for (int r = 0; r < 4; ++r) {
                    int t = mt * 16 + sub * 4 + r;
                    if (t < TOK) sW[t * SX_ST + c] += acc2[i][mt][r] + bias;
                }
        }
    }
    __syncthreads();   // final

    // ---- P10: window-reverse store (lane = spatial token) ----
    if (lane < TOK) {
        float* ys = y + xbase + (size_t)(row0 + li7) * IMG + (col0 + lj7);
        const float* src = sW + lane * SX_ST;
        #pragma unroll 8
        for (int c = wid; c < CH; c += 8)
            ys[(size_t)c * (IMG * IMG)] = src[c];
    }
}

extern "C" void kernel_launch(void* const* d_in, const int* in_sizes, int n_in,
                              void* d_out, int out_size, void* d_ws, size_t ws_size,
                              hipStream_t stream) {
    const float* x      = (const float*)d_in[0];
    const float* ln1_g  = (const float*)d_in[1];
    const float* ln1_b  = (const float*)d_in[2];
    const float* qkv_w  = (const float*)d_in[3];
    const float* qkv_b  = (const float*)d_in[4];
    const float* proj_w = (const float*)d_in[5];
    const float* proj_b = (const float*)d_in[6];
    const float* ln2_g  = (const float*)d_in[7];
    const float* ln2_b  = (const float*)d_in[8];
    const float* w1     = (const float*)d_in[9];
    const float* b1     = (const float*)d_in[10];
    const float* w2     = (const float*)d_in[11];
    const float* b2     = (const float*)d_in[12];

    hipLaunchKernelGGL(prepack, dim3(1024), dim3(64), 0, stream,
                       qkv_w, proj_w, w1, w2, (char*)d_ws);
    hipLaunchKernelGGL(swin_block, dim3(NWIN), dim3(NTHR), 0, stream,
                       x, ln1_g, ln1_b, qkv_b, proj_b, ln2_g, ln2_b, b1, b2,
                       (const char*)d_ws, (float*)d_out);
}

// Round 16
// 643.965 us; speedup vs baseline: 1.2673x; 1.0620x over previous
//
#include <hip/hip_runtime.h>
#include <hip/hip_bf16.h>

typedef __bf16 bf16x8 __attribute__((ext_vector_type(8)));
typedef float  f32x4  __attribute__((ext_vector_type(4)));
typedef unsigned short u16x8 __attribute__((ext_vector_type(8)));

#define CH    256
#define IMG   112
#define WSZ   7
#define TOK   49
#define NWIN  4096
#define HID   512
#define NTHR  512

#define SX_ST 260          // f32 row stride for sX (permanent window buffer)

// ---- LDS arena (byte offsets), time-multiplexed ----
// [0, 51200)        sX f32 (whole kernel; becomes win2 in place at P6)
// [51200, 83968)    n1F frags -> (3b) V frags -> n2F frags
// [83968, 116736)   Q frags -> (4a) P bufs -> HM half-1
// [116736, 149504)  K frags -> (4a) OF frags -> HM half-0
#define OFF_AF   51200
#define OFF_V    51200
#define OFF_Q    83968
#define OFF_P    83968
#define PSZ      7168
#define OFF_HM1  83968
#define OFF_K    116736
#define OFF_OF   116736
#define OFF_HM0  116736
#define OFF_MR   149504     // sM[64], sR[64]
#define OFF_PRM  150016     // sG1,sB1,sG2,sB2 (each 256 f32)
#define OFF_PART 154112     // float2[49*8] LN partials
#define SMEM_SZ  157248

// ---- d_ws layout: bf16 B-fragment blocks, 1KB each ----
#define WS_PROJ_BLK 384
#define WS_W1_BLK   512
#define WS_W2_BLK   768

__device__ __forceinline__ unsigned short f2bf(float f) {
    __bf16 h = (__bf16)f;
    return __builtin_bit_cast(unsigned short, h);
}

__device__ __forceinline__ f32x4 mfma16(bf16x8 a, bf16x8 b, f32x4 c) {
    return __builtin_amdgcn_mfma_f32_16x16x32_bf16(a, b, c, 0, 0, 0);
}

__device__ __forceinline__ int frOff(int base, int t, int c) {
    return base + (((t >> 4) * 8 + (c >> 5)) << 10)
                + (((((c >> 3) & 3) << 4) | (t & 15)) << 4)
                + ((c & 7) << 1);
}
__device__ __forceinline__ int frOffT(int base, int c, int t) {
    return base + ((((c >> 4) << 1) + (t >> 5)) << 10)
                + (((((t >> 3) & 3) << 4) | (c & 15)) << 4)
                + ((t & 7) << 1);
}

// ---------------- prepack: fp32 weights -> bf16 B-fragment blocks in d_ws ----------------
extern "C" __global__ __launch_bounds__(64)
void prepack(const float* __restrict__ qkv_w, const float* __restrict__ proj_w,
             const float* __restrict__ w1, const float* __restrict__ w2,
             char* __restrict__ ws)
{
    const int blk = blockIdx.x, l = threadIdx.x;
    const float* W; int nt, kt, ncols;
    if (blk < WS_PROJ_BLK)      { W = qkv_w;  int i = blk;               nt = i >> 3; kt = i & 7;  ncols = 768; }
    else if (blk < WS_W1_BLK)   { W = proj_w; int i = blk - WS_PROJ_BLK; nt = i >> 3; kt = i & 7;  ncols = 256; }
    else if (blk < WS_W2_BLK)   { W = w1;     int i = blk - WS_W1_BLK;   nt = i >> 3; kt = i & 7;  ncols = 512; }
    else                        { W = w2;     int i = blk - WS_W2_BLK;   nt = i >> 4; kt = i & 15; ncols = 256; }
    const int n  = nt * 16 + (l & 15);
    const int k0 = kt * 32 + (l >> 4) * 8;
    u16x8 o;
    #pragma unroll
    for (int j = 0; j < 8; ++j) o[j] = f2bf(W[(size_t)(k0 + j) * ncols + n]);
    *(u16x8*)(ws + (size_t)blk * 1024 + l * 16) = o;
}

// ---------------- main fused block: 8 waves, XCD swizzle, double-buffered MLP ----------------
extern "C" __global__ __launch_bounds__(NTHR, 1)
void swin_block(const float* __restrict__ x,
                const float* __restrict__ ln1_g, const float* __restrict__ ln1_b,
                const float* __restrict__ qkv_b,
                const float* __restrict__ proj_b,
                const float* __restrict__ ln2_g, const float* __restrict__ ln2_b,
                const float* __restrict__ b1, const float* __restrict__ b2,
                const char* __restrict__ ws,
                float* __restrict__ y)
{
    __shared__ __align__(16) char smem[SMEM_SZ];
    float*  sX = (float*)(smem + 0);          // persistent; becomes win2 in place
    float*  sM = (float*)(smem + OFF_MR);
    float*  sR = sM + 64;
    float*  sG1 = (float*)(smem + OFF_PRM);
    float*  sB1 = sG1 + 256;
    float*  sG2 = sB1 + 256;
    float*  sB2 = sG2 + 256;
    float2* sPart = (float2*)(smem + OFF_PART);

    const int tid  = threadIdx.x;
    const int wid  = tid >> 6;       // 0..7
    const int lane = tid & 63;
    const int sub  = lane >> 4;
    const int l15  = lane & 15;
    const int li7  = lane / 7;       // spatial row (lane<49)
    const int lj7  = lane - li7 * 7; // spatial col

    // XCD-aware swizzle: each XCD gets a contiguous run of 512 windows (2 images)
    const int bid = blockIdx.x;
    const int n  = (bid & 7) * (NWIN / 8) + (bid >> 3);
    const int b  = n >> 8;
    const int wh = (n >> 4) & 15;
    const int ww = n & 15;
    const int row0 = wh * WSZ, col0 = ww * WSZ;
    const size_t xbase = (size_t)b * CH * IMG * IMG;

    const f32x4 z4 = {0.f, 0.f, 0.f, 0.f};

    bf16x8 pbF0[8];      // proj tile-0 weights (filled in P4, consumed in P6)

    // ---- P0: stage x -> sX with fused LN1 partial sums ----
    {
        float ps1 = 0.f, ps2 = 0.f;
        if (lane < TOK) {
            const float* xs = x + xbase + (size_t)(row0 + li7) * IMG + (col0 + lj7);
            float* dst = sX + lane * SX_ST;
            #pragma unroll 8
            for (int c = wid; c < CH; c += 8) {
                float v = xs[(size_t)c * (IMG * IMG)];
                dst[c] = v;
                ps1 += v; ps2 += v * v;
            }
        }
        int t2 = tid & 255;
        if (tid < 256) { sG1[t2] = ln1_g[t2]; sB1[t2] = ln1_b[t2]; }
        else           { sG2[t2] = ln2_g[t2]; sB2[t2] = ln2_b[t2]; }
        if (lane < TOK) sPart[lane * 8 + wid] = make_float2(ps1, ps2);
    }
    __syncthreads();   // 1

    // ---- P1: LN1 finalize (tiny) ----
    if (tid < TOK) {
        float s1 = 0.f, s2 = 0.f;
        #pragma unroll
        for (int w = 0; w < 8; ++w) {
            float2 q = sPart[tid * 8 + w];
            s1 += q.x; s2 += q.y;
        }
        float m = s1 * (1.f / 256.f);
        float var = s2 * (1.f / 256.f) - m * m;
        sM[tid] = m; sR[tid] = rsqrtf(var + 1e-5f);
    }
    __syncthreads();   // 2

    // prefetch first QKV B-batch (latency hides under P2; drains at barrier 3)
    bf16x8 bA[8], bB[8];
    #pragma unroll
    for (int kt = 0; kt < 8; ++kt)
        bA[kt] = *(const bf16x8*)(ws + (size_t)(((wid * 6) * 8 + kt) << 10) + lane * 16);

    // ---- P2: normalize -> n1F fragment blocks; zero pad rows (needed: V pads derive from these) ----
    for (int e = tid; e < 2048; e += NTHR) {
        int t = e & 63, cb = e >> 6;
        char* dst = smem + OFF_AF + (((t >> 4) * 8 + (cb >> 2)) << 10)
                  + (((((cb & 3) << 4) | (t & 15))) << 4);
        if (t < TOK) {
            const float* xr = sX + t * SX_ST + cb * 8;
            float4 xa = *(const float4*)xr;
            float4 xb = *(const float4*)(xr + 4);
            float m = sM[t], rs = sR[t];
            int c = cb * 8;
            u16x8 o;
            o[0] = f2bf((xa.x - m) * rs * sG1[c + 0] + sB1[c + 0]);
            o[1] = f2bf((xa.y - m) * rs * sG1[c + 1] + sB1[c + 1]);
            o[2] = f2bf((xa.z - m) * rs * sG1[c + 2] + sB1[c + 2]);
            o[3] = f2bf((xa.w - m) * rs * sG1[c + 3] + sB1[c + 3]);
            o[4] = f2bf((xb.x - m) * rs * sG1[c + 4] + sB1[c + 4]);
            o[5] = f2bf((xb.y - m) * rs * sG1[c + 5] + sB1[c + 5]);
            o[6] = f2bf((xb.z - m) * rs * sG1[c + 6] + sB1[c + 6]);
            o[7] = f2bf((xb.w - m) * rs * sG1[c + 7] + sB1[c + 7]);
            *(u16x8*)dst = o;
        } else {
            u16x8 z = {0, 0, 0, 0, 0, 0, 0, 0};
            *(u16x8*)dst = z;
        }
    }
    __syncthreads();   // 3

    // ---- P3: QKV GEMM (M=64,N=768,K=256); V frags overwrite n1F region after 3b ----
    {
        bf16x8 aF[4][8];
        #pragma unroll
        for (int mt = 0; mt < 4; ++mt)
            #pragma unroll
            for (int kt = 0; kt < 8; ++kt)
                aF[mt][kt] = *(const bf16x8*)(smem + OFF_AF + ((mt * 8 + kt) << 10) + lane * 16);
        __syncthreads();   // 3b: all waves hold n1F in regs; V may overwrite region

        auto qkv_epi = [&](int ntg, const f32x4 (&acc)[4]) {
            const float bias = qkv_b[ntg * 16 + l15];
            const int m3 = ntg >> 4;              // 0=Q 1=K 2=V
            const int c = (ntg & 15) * 16 + l15;
            if (m3 == 2) {
                #pragma unroll
                for (int mt = 0; mt < 4; ++mt)
                    #pragma unroll
                    for (int r = 0; r < 4; ++r) {
                        int t = mt * 16 + sub * 4 + r;
                        *(unsigned short*)(smem + frOffT(OFF_V, c, t)) = f2bf(acc[mt][r] + bias);
                    }
            } else if (m3 == 1) {
                #pragma unroll
                for (int mt = 0; mt < 4; ++mt)
                    #pragma unroll
                    for (int r = 0; r < 4; ++r) {
                        int t = mt * 16 + sub * 4 + r;
                        *(unsigned short*)(smem + frOff(OFF_K, t, c)) = f2bf(acc[mt][r] + bias);
                    }
            } else {
                #pragma unroll
                for (int mt = 0; mt < 4; ++mt)
                    #pragma unroll
                    for (int r = 0; r < 4; ++r) {
                        int t = mt * 16 + sub * 4 + r;
                        *(unsigned short*)(smem + frOff(OFF_Q, t, c)) = f2bf((acc[mt][r] + bias) * 0.125f);
                    }
            }
        };

        for (int i = 0; i < 6; i += 2) {
            const int n0 = wid * 6 + i;
            #pragma unroll
            for (int kt = 0; kt < 8; ++kt)
                bB[kt] = *(const bf16x8*)(ws + (size_t)(((n0 + 1) * 8 + kt) << 10) + lane * 16);
            {
                f32x4 acc[4] = {z4, z4, z4, z4};
                #pragma unroll
                for (int kt = 0; kt < 8; ++kt)
                    #pragma unroll
                    for (int mt = 0; mt < 4; ++mt)
                        acc[mt] = mfma16(aF[mt][kt], bA[kt], acc[mt]);
                qkv_epi(n0, acc);
            }
            if (i + 2 < 6) {
                #pragma unroll
                for (int kt = 0; kt < 8; ++kt)
                    bA[kt] = *(const bf16x8*)(ws + (size_t)(((n0 + 2) * 8 + kt) << 10) + lane * 16);
            }
            {
                f32x4 acc[4] = {z4, z4, z4, z4};
                #pragma unroll
                for (int kt = 0; kt < 8; ++kt)
                    #pragma unroll
                    for (int mt = 0; mt < 4; ++mt)
                        acc[mt] = mfma16(aF[mt][kt], bB[kt], acc[mt]);
                qkv_epi(n0 + 1, acc);
            }
        }
    }
    __syncthreads();   // 4

    // ---- P4: attention; wave = (head h = wid>>1, m-half ah = wid&1) ----
    {
        const int h  = wid >> 1;
        const int ah = wid & 1;
        f32x4 sc[2][4];
        #pragma unroll
        for (int m = 0; m < 2; ++m)
            #pragma unroll
            for (int nt = 0; nt < 4; ++nt) sc[m][nt] = z4;

        {
            bf16x8 qf[2][2], kf[4][2];
            #pragma unroll
            for (int m = 0; m < 2; ++m)
                #pragma unroll
                for (int k2 = 0; k2 < 2; ++k2)
                    qf[m][k2] = *(const bf16x8*)(smem + OFF_Q + (((ah * 2 + m) * 8 + h * 2 + k2) << 10) + lane * 16);
            #pragma unroll
            for (int nt = 0; nt < 4; ++nt)
                #pragma unroll
                for (int k2 = 0; k2 < 2; ++k2)
                    kf[nt][k2] = *(const bf16x8*)(smem + OFF_K + ((nt * 8 + h * 2 + k2) << 10) + lane * 16);
            #pragma unroll
            for (int k2 = 0; k2 < 2; ++k2)
                #pragma unroll
                for (int m = 0; m < 2; ++m)
                    #pragma unroll
                    for (int nt = 0; nt < 4; ++nt)
                        sc[m][nt] = mfma16(qf[m][k2], kf[nt][k2], sc[m][nt]);
        }
        __syncthreads();   // 4a: Q/K reads drained (P may overwrite Q region; OF may overwrite K region)

        // cross-barrier prefetch: proj tile-0 weights (consumed in P6; hides under softmax/PV)
        #pragma unroll
        for (int kt = 0; kt < 8; ++kt)
            pbF0[kt] = *(const bf16x8*)(ws + (size_t)(((WS_PROJ_BLK + (wid * 2) * 8 + kt)) << 10) + lane * 16);

        const int pbase = OFF_P + h * PSZ;
        #pragma unroll
        for (int m = 0; m < 2; ++m) {
            #pragma unroll
            for (int r = 0; r < 4; ++r) {
                const int t = (ah * 2 + m) * 16 + sub * 4 + r;
                float v0 = sc[m][0][r];
                float v1 = sc[m][1][r];
                float v2 = sc[m][2][r];
                float v3 = (l15 == 0) ? sc[m][3][r] : -1e30f;
                float mx = fmaxf(fmaxf(v0, v1), fmaxf(v2, v3));
                mx = fmaxf(mx, __shfl_xor(mx, 1));
                mx = fmaxf(mx, __shfl_xor(mx, 2));
                mx = fmaxf(mx, __shfl_xor(mx, 4));
                mx = fmaxf(mx, __shfl_xor(mx, 8));
                float e0 = __expf(v0 - mx), e1 = __expf(v1 - mx);
                float e2 = __expf(v2 - mx), e3 = __expf(v3 - mx);
                float s = e0 + e1 + e2 + e3;
                s += __shfl_xor(s, 1);
                s += __shfl_xor(s, 2);
                s += __shfl_xor(s, 4);
                s += __shfl_xor(s, 8);
                float inv = 1.f / s;
                if (t < TOK) {
                    unsigned short* pr = (unsigned short*)(smem + pbase + t * 144);
                    pr[l15]      = f2bf(e0 * inv);
                    pr[16 + l15] = f2bf(e1 * inv);
                    pr[32 + l15] = f2bf(e2 * inv);
                    pr[48 + l15] = f2bf(e3 * inv);
                }
            }
        }

        // PV: O_h rows of this m-half (P rows wave-local: same-wave write->read)
        bf16x8 pf[2][2], vf[4][2];
        #pragma unroll
        for (int m = 0; m < 2; ++m)
            #pragma unroll
            for (int k2 = 0; k2 < 2; ++k2) {
                int row = (ah * 2 + m) * 16 + l15; row = row > 48 ? 48 : row;
                pf[m][k2] = *(const bf16x8*)(smem + pbase + row * 144 + ((k2 * 32 + sub * 8) << 1));
            }
        #pragma unroll
        for (int nt = 0; nt < 4; ++nt)
            #pragma unroll
            for (int k2 = 0; k2 < 2; ++k2)
                vf[nt][k2] = *(const bf16x8*)(smem + OFF_V + ((((h * 4 + nt) << 1) + k2) << 10) + lane * 16);

        f32x4 oc[2][4];
        #pragma unroll
        for (int m = 0; m < 2; ++m)
            #pragma unroll
            for (int nt = 0; nt < 4; ++nt) oc[m][nt] = z4;
        #pragma unroll
        for (int k2 = 0; k2 < 2; ++k2)
            #pragma unroll
            for (int m = 0; m < 2; ++m)
                #pragma unroll
                for (int nt = 0; nt < 4; ++nt)
                    oc[m][nt] = mfma16(pf[m][k2], vf[nt][k2], oc[m][nt]);
        #pragma unroll
        for (int m = 0; m < 2; ++m)
            #pragma unroll
            for (int nt = 0; nt < 4; ++nt)
                #pragma unroll
                for (int r = 0; r < 4; ++r) {
                    int t = (ah * 2 + m) * 16 + sub * 4 + r;
                    int c = h * 64 + nt * 16 + l15;
                    *(unsigned short*)(smem + frOff(OFF_OF, t, c)) = f2bf(oc[m][nt][r]);
                }
    }
    __syncthreads();   // 5

    // ---- P6: proj + residual RMW into persistent sX, LN2 partials fused ----
    float* sW = sX;
    {
        bf16x8 pbF1[8];
        #pragma unroll
        for (int kt = 0; kt < 8; ++kt)
            pbF1[kt] = *(const bf16x8*)(ws + (size_t)(((WS_PROJ_BLK + (wid * 2 + 1) * 8 + kt)) << 10) + lane * 16);

        bf16x8 aF[4][8];
        #pragma unroll
        for (int mt = 0; mt < 4; ++mt)
            #pragma unroll
            for (int kt = 0; kt < 8; ++kt)
                aF[mt][kt] = *(const bf16x8*)(smem + OFF_OF + ((mt * 8 + kt) << 10) + lane * 16);

        // epi: RMW sW, inline per-t reduce over this wave's 16 channels, accumulate sPart
        auto proj_epi = [&](int ntg, const f32x4 (&acc)[4], bool first) {
            const int c = ntg * 16 + l15;
            const float bias = proj_b[c];
            #pragma unroll
            for (int mt = 0; mt < 4; ++mt)
                #pragma unroll
                for (int r = 0; r < 4; ++r) {
                    int t = mt * 16 + sub * 4 + r;
                    if (t < TOK) {
                        float w = sW[t * SX_ST + c] + acc[mt][r] + bias;
                        sW[t * SX_ST + c] = w;
                        float a = w, bb = w * w;
                        a += __shfl_xor(a, 1); bb += __shfl_xor(bb, 1);
                        a += __shfl_xor(a, 2); bb += __shfl_xor(bb, 2);
                        a += __shfl_xor(a, 4); bb += __shfl_xor(bb, 4);
                        a += __shfl_xor(a, 8); bb += __shfl_xor(bb, 8);
                        if (l15 == 0) {
                            if (first) {
                                sPart[t * 8 + wid] = make_float2(a, bb);
                            } else {
                                float2 q = sPart[t * 8 + wid];
                                sPart[t * 8 + wid] = make_float2(q.x + a, q.y + bb);
                            }
                        }
                    }
                }
        };

        {
            f32x4 acc[4] = {z4, z4, z4, z4};
            #pragma unroll
            for (int kt = 0; kt < 8; ++kt)
                #pragma unroll
                for (int mt = 0; mt < 4; ++mt)
                    acc[mt] = mfma16(aF[mt][kt], pbF0[kt], acc[mt]);
            proj_epi(wid * 2, acc, true);
        }
        {
            f32x4 acc[4] = {z4, z4, z4, z4};
            #pragma unroll
            for (int kt = 0; kt < 8; ++kt)
                #pragma unroll
                for (int mt = 0; mt < 4; ++mt)
                    acc[mt] = mfma16(aF[mt][kt], pbF1[kt], acc[mt]);
            proj_epi(wid * 2 + 1, acc, false);
        }
    }
    __syncthreads();   // 6

    // ---- P7: LN2 finalize (tiny) ----
    if (tid < TOK) {
        float s1 = 0.f, s2 = 0.f;
        #pragma unroll
        for (int w = 0; w < 8; ++w) {
            float2 q = sPart[tid * 8 + w];
            s1 += q.x; s2 += q.y;
        }
        float m = s1 * (1.f / 256.f);
        float var = s2 * (1.f / 256.f) - m * m;
        sM[tid] = m; sR[tid] = rsqrtf(var + 1e-5f);
    }
    __syncthreads();   // 7

    // ---- P8: LN2 normalize -> n2F (pad rows left stale: all consumers t<TOK-guarded) ----
    for (int e = tid; e < 2048; e += NTHR) {
        int t = e & 63, cb = e >> 6;
        if (t < TOK) {
            char* dst = smem + OFF_AF + (((t >> 4) * 8 + (cb >> 2)) << 10)
                      + (((((cb & 3) << 4) | (t & 15))) << 4);
            const float* xr = sW + t * SX_ST + cb * 8;
            float4 xa = *(const float4*)xr;
            float4 xb = *(const float4*)(xr + 4);
            float m = sM[t], rs = sR[t];
            int c = cb * 8;
            u16x8 o;
            o[0] = f2bf((xa.x - m) * rs * sG2[c + 0] + sB2[c + 0]);
            o[1] = f2bf((xa.y - m) * rs * sG2[c + 1] + sB2[c + 1]);
            o[2] = f2bf((xa.z - m) * rs * sG2[c + 2] + sB2[c + 2]);
            o[3] = f2bf((xa.w - m) * rs * sG2[c + 3] + sB2[c + 3]);
            o[4] = f2bf((xb.x - m) * rs * sG2[c + 4] + sB2[c + 4]);
            o[5] = f2bf((xb.y - m) * rs * sG2[c + 5] + sB2[c + 5]);
            o[6] = f2bf((xb.z - m) * rs * sG2[c + 6] + sB2[c + 6]);
            o[7] = f2bf((xb.w - m) * rs * sG2[c + 7] + sB2[c + 7]);
            *(u16x8*)dst = o;
        }
    }
    __syncthreads();   // 8

    // ---- P9: MLP, double-buffered: HM0 in OF region, HM1 in Q region (2 barriers total) ----
    {
        f32x4 acc2[2][4];
        #pragma unroll
        for (int i = 0; i < 2; ++i)
            #pragma unroll
            for (int mt = 0; mt < 4; ++mt) acc2[i][mt] = z4;

        auto mlp1_half = [&](int half, int hmBase) {
            bf16x8 bF0[8], bF1[8];
            #pragma unroll
            for (int kt = 0; kt < 8; ++kt) {
                bF0[kt] = *(const bf16x8*)(ws + (size_t)(((WS_W1_BLK + (half * 16 + wid * 2) * 8 + kt)) << 10) + lane * 16);
                bF1[kt] = *(const bf16x8*)(ws + (size_t)(((WS_W1_BLK + (half * 16 + wid * 2 + 1) * 8 + kt)) << 10) + lane * 16);
            }
            #pragma unroll
            for (int mh = 0; mh < 2; ++mh) {
                bf16x8 nf[2][8];
                #pragma unroll
                for (int mm = 0; mm < 2; ++mm)
                    #pragma unroll
                    for (int kt = 0; kt < 8; ++kt)
                        nf[mm][kt] = *(const bf16x8*)(smem + OFF_AF + (((mh * 2 + mm) * 8 + kt) << 10) + lane * 16);

                f32x4 a0[2] = {z4, z4}, a1[2] = {z4, z4};
                #pragma unroll
                for (int kt = 0; kt < 8; ++kt)
                    #pragma unroll
                    for (int mm = 0; mm < 2; ++mm) {
                        a0[mm] = mfma16(nf[mm][kt], bF0[kt], a0[mm]);
                        a1[mm] = mfma16(nf[mm][kt], bF1[kt], a1[mm]);
                    }

                #pragma unroll
                for (int tile = 0; tile < 2; ++tile) {
                    const int ntg = wid * 2 + tile;
                    const int chm = ntg * 16 + l15;
                    const float bias = b1[half * 256 + chm];
                    #pragma unroll
                    for (int mm = 0; mm < 2; ++mm)
                        #pragma unroll
                        for (int r = 0; r < 4; ++r) {
                            int t = (mh * 2 + mm) * 16 + sub * 4 + r;
                            if (t < TOK) {
                                float v = (tile ? a1[mm][r] : a0[mm][r]) + bias;
                                float u = v * (1.5957691216f + 0.07135481627f * v * v);
                                float g = v / (1.f + __expf(-u));
                                *(unsigned short*)(smem + frOff(hmBase, t, chm)) = f2bf(g);
                            }
                        }
                }
            }
        };

        auto mlp2_half = [&](int half, int hmBase) {
            bf16x8 bF0[8], bF1[8];
            #pragma unroll
            for (int kt = 0; kt < 8; ++kt) {
                bF0[kt] = *(const bf16x8*)(ws + (size_t)(((WS_W2_BLK + (wid * 2 + 0) * 16 + half * 8 + kt)) << 10) + lane * 16);
                bF1[kt] = *(const bf16x8*)(ws + (size_t)(((WS_W2_BLK + (wid * 2 + 1) * 16 + half * 8 + kt)) << 10) + lane * 16);
            }
            #pragma unroll
            for (int mh = 0; mh < 2; ++mh) {
                bf16x8 hf[2][8];
                #pragma unroll
                for (int mm = 0; mm < 2; ++mm)
                    #pragma unroll
                    for (int kt = 0; kt < 8; ++kt)
                        hf[mm][kt] = *(const bf16x8*)(smem + hmBase + (((mh * 2 + mm) * 8 + kt) << 10) + lane * 16);
                #pragma unroll
                for (int kt = 0; kt < 8; ++kt)
                    #pragma unroll
                    for (int mm = 0; mm < 2; ++mm) {
                        acc2[0][mh * 2 + mm] = mfma16(hf[mm][kt], bF0[kt], acc2[0][mh * 2 + mm]);
                        acc2[1][mh * 2 + mm] = mfma16(hf[mm][kt], bF1[kt], acc2[1][mh * 2 + mm]);
                    }
            }
        };

        mlp1_half(0, OFF_HM0);     // writes OF region (dead after P6)
        __syncthreads();           // 9a: HM0 ready
        mlp2_half(0, OFF_HM0);     // MFMA-dense...
        mlp1_half(1, OFF_HM1);     // ...overlaps VALU-dense GELU (disjoint regions)
        __syncthreads();           // 9b: HM1 ready (HM0 reads done; regions disjoint anyway)
        mlp2_half(1, OFF_HM1);

        // epilogue: win2 += mlp2 + b2
        #pragma unroll
        for (int i = 0; i < 2; ++i) {
            const int c = (wid * 2 + i) * 16 + l15;
            const float bias = b2[c];
            #pragma unroll
            for (int mt = 0; mt < 4; ++mt)
                #pragma unroll
                for (int r = 0; r < 4; ++r) {
                    int t = mt * 16 + sub * 4 + r;
                    if (t < TOK) sW[t * SX_ST + c] += acc2[i][mt][r] + bias;
                }
        }
    }
    __syncthreads();   // final

    // ---- P10: window-reverse store (lane = spatial token) ----
    if (lane < TOK) {
        float* ys = y + xbase + (size_t)(row0 + li7) * IMG + (col0 + lj7);
        const float* src = sW + lane * SX_ST;
        #pragma unroll 8
        for (int c = wid; c < CH; c += 8)
            ys[(size_t)c * (IMG * IMG)] = src[c];
    }
}

extern "C" void kernel_launch(void* const* d_in, const int* in_sizes, int n_in,
                              void* d_out, int out_size, void* d_ws, size_t ws_size,
                              hipStream_t stream) {
    const float* x      = (const float*)d_in[0];
    const float* ln1_g  = (const float*)d_in[1];
    const float* ln1_b  = (const float*)d_in[2];
    const float* qkv_w  = (const float*)d_in[3];
    const float* qkv_b  = (const float*)d_in[4];
    const float* proj_w = (const float*)d_in[5];
    const float* proj_b = (const float*)d_in[6];
    const float* ln2_g  = (const float*)d_in[7];
    const float* ln2_b  = (const float*)d_in[8];
    const float* w1     = (const float*)d_in[9];
    const float* b1     = (const float*)d_in[10];
    const float* w2     = (const float*)d_in[11];
    const float* b2     = (const float*)d_in[12];

    hipLaunchKernelGGL(prepack, dim3(1024), dim3(64), 0, stream,
                       qkv_w, proj_w, w1, w2, (char*)d_ws);
    hipLaunchKernelGGL(swin_block, dim3(NWIN), dim3(NTHR), 0, stream,
                       x, ln1_g, ln1_b, qkv_b, proj_b, ln2_g, ln2_b, b1, b2,
                       (const char*)d_ws, (float*)d_out);
}